// Round 9
// baseline (2069.496 us; speedup 1.0000x reference)
//
#include <hip/hip_runtime.h>
#include <math.h>

#define NA 131072   // atoms
#define NE 262144   // edges
#define NG 4096     // graphs
#define FN 30
#define FE 11
#define H  256
#define H2 512
#define NL 5
#define BN_EPS 1e-5f

typedef _Float16 f16x8 __attribute__((ext_vector_type(8)));
typedef _Float16 f16x4 __attribute__((ext_vector_type(4)));
typedef float f32x4 __attribute__((ext_vector_type(4)));

// ---- private fallback workspace, allocated ONCE at library load ----
static char* g_buf = nullptr;
__attribute__((constructor)) static void _alloc_private_ws() {
    void* p = nullptr;
    if (hipMalloc(&p, (size_t)320 * 1024 * 1024) == hipSuccess) g_buf = (char*)p;
}

// ---------------- weight prep: transpose to fp16 [N][K] ----------------
__global__ __launch_bounds__(256) void prep_w(const float* __restrict__ w, int K, int N,
                                              _Float16* __restrict__ hT) {
    __shared__ float t[32][33];
    const int k0 = blockIdx.x * 32, n0 = blockIdx.y * 32;
    const int tx = threadIdx.x & 31, ty = threadIdx.x >> 5;   // ty 0..7
    #pragma unroll
    for (int i = 0; i < 4; ++i)
        t[ty + i * 8][tx] = w[(size_t)(k0 + ty + i * 8) * N + n0 + tx];
    __syncthreads();
    #pragma unroll
    for (int i = 0; i < 4; ++i)
        hT[(size_t)(n0 + ty + i * 8) * K + k0 + tx] = (_Float16)t[tx][ty + i * 8];
}

// ---------------- node encoder: 4 rows/block, fp16 out ----------------
__global__ __launch_bounds__(256) void encode_nodes(const float* __restrict__ x,
                                                    const float* __restrict__ w,
                                                    const float* __restrict__ b,
                                                    _Float16* __restrict__ h16) {
    __shared__ float xs[4 * FN];
    const int t = threadIdx.x;
    const int blk = blockIdx.x;
    if (t < 4 * FN) xs[t] = x[(size_t)blk * 4 * FN + t];
    __syncthreads();
    const int rr = t >> 6;
    const int lane = t & 63;
    const int c = lane * 4;
    const float* xr = &xs[rr * FN];
    float4 acc = *(const float4*)(b + c);
    #pragma unroll
    for (int k = 0; k < FN; ++k) {
        const float a = xr[k];
        const float4 wv = *(const float4*)(w + (size_t)k * H + c);
        acc.x += a * wv.x; acc.y += a * wv.y; acc.z += a * wv.z; acc.w += a * wv.w;
    }
    f16x4 o;
    o.x = (_Float16)acc.x; o.y = (_Float16)acc.y;
    o.z = (_Float16)acc.z; o.w = (_Float16)acc.w;
    *(f16x4*)(h16 + (size_t)(blk * 4 + rr) * H + c) = o;
}

// ---------------- CSR build (once per call) ----------------
__global__ __launch_bounds__(256) void count_deg(const int* __restrict__ ei,
                                                 int* __restrict__ deg) {
    const int e = blockIdx.x * 256 + threadIdx.x;
    if (e < NE) atomicAdd(&deg[ei[NE + e]], 1);
}

__global__ __launch_bounds__(1024) void scan_deg(const int* __restrict__ deg,
                                                 int* __restrict__ rowptr,
                                                 int* __restrict__ cursor) {
    __shared__ int part[1024];
    const int t = threadIdx.x;
    const int base = t * 128;               // 1024*128 == NA
    int s = 0;
    #pragma unroll 8
    for (int i = 0; i < 128; ++i) s += deg[base + i];
    part[t] = s;
    __syncthreads();
    for (int off = 1; off < 1024; off <<= 1) {
        const int v = (t >= off) ? part[t - off] : 0;
        __syncthreads();
        part[t] += v;
        __syncthreads();
    }
    int run = (t == 0) ? 0 : part[t - 1];
    #pragma unroll 8
    for (int i = 0; i < 128; ++i) {
        rowptr[base + i] = run;
        cursor[base + i] = run;
        run += deg[base + i];
    }
    if (t == 1023) rowptr[NA] = run;        // == NE
}

__global__ __launch_bounds__(256) void fill_elist(const int* __restrict__ ei,
                                                  int* __restrict__ cursor,
                                                  int2* __restrict__ se) {
    const int e = blockIdx.x * 256 + threadIdx.x;
    if (e < NE) {
        const int src = ei[e];
        const int pos = atomicAdd(&cursor[ei[NE + e]], 1);
        se[pos] = make_int2(src, e);
    }
}

// ---- GINE aggregation v3: 2 dsts per wave, interleaved dependent chains ----
__global__ __launch_bounds__(256) void gine_msg(const _Float16* __restrict__ h16,
                                                const float* __restrict__ eattr,
                                                const float* __restrict__ bond_w,
                                                const float* __restrict__ bond_b,
                                                const int2* __restrict__ se,
                                                const int* __restrict__ rowptr,
                                                const float* __restrict__ eps, int l,
                                                _Float16* __restrict__ z) {
    const int wv = blockIdx.x * 4 + (threadIdx.x >> 6);
    const int d0 = wv * 2, d1 = d0 + 1;
    const int lane = threadIdx.x & 63;
    const int c = lane * 4;
    float4 wb[FE];
    #pragma unroll
    for (int k = 0; k < FE; ++k) wb[k] = *(const float4*)(bond_w + k * H + c);
    const float4 bb = *(const float4*)(bond_b + c);
    const float sc = 1.0f + eps[l];
    const f16x4 hv0 = *(const f16x4*)(h16 + (size_t)d0 * H + c);
    const f16x4 hv1 = *(const f16x4*)(h16 + (size_t)d1 * H + c);
    float4 acc0, acc1;
    acc0.x = sc * (float)hv0.x; acc0.y = sc * (float)hv0.y;
    acc0.z = sc * (float)hv0.z; acc0.w = sc * (float)hv0.w;
    acc1.x = sc * (float)hv1.x; acc1.y = sc * (float)hv1.y;
    acc1.z = sc * (float)hv1.z; acc1.w = sc * (float)hv1.w;
    int t0 = rowptr[d0];
    const int e0 = rowptr[d0 + 1];
    int t1 = e0;                          // rowptr[d1] == rowptr[d0+1]
    const int e1 = rowptr[d1 + 1];
    while ((t0 < e0) || (t1 < e1)) {
        const bool p0 = t0 < e0, p1 = t1 < e1;
        const int2 s0 = se[p0 ? t0 : 0];
        const int2 s1 = se[p1 ? t1 : 0];
        const f16x4 g0 = *(const f16x4*)(h16 + (size_t)s0.x * H + c);
        const f16x4 g1 = *(const f16x4*)(h16 + (size_t)s1.x * H + c);
        float4 ev0 = bb, ev1 = bb;
        #pragma unroll
        for (int k = 0; k < FE; ++k) {
            const float a0 = eattr[(size_t)s0.y * FE + k];
            const float a1 = eattr[(size_t)s1.y * FE + k];
            ev0.x += a0 * wb[k].x; ev0.y += a0 * wb[k].y;
            ev0.z += a0 * wb[k].z; ev0.w += a0 * wb[k].w;
            ev1.x += a1 * wb[k].x; ev1.y += a1 * wb[k].y;
            ev1.z += a1 * wb[k].z; ev1.w += a1 * wb[k].w;
        }
        if (p0) {
            acc0.x += fmaxf((float)g0.x + ev0.x, 0.0f);
            acc0.y += fmaxf((float)g0.y + ev0.y, 0.0f);
            acc0.z += fmaxf((float)g0.z + ev0.z, 0.0f);
            acc0.w += fmaxf((float)g0.w + ev0.w, 0.0f);
            ++t0;
        }
        if (p1) {
            acc1.x += fmaxf((float)g1.x + ev1.x, 0.0f);
            acc1.y += fmaxf((float)g1.y + ev1.y, 0.0f);
            acc1.z += fmaxf((float)g1.z + ev1.z, 0.0f);
            acc1.w += fmaxf((float)g1.w + ev1.w, 0.0f);
            ++t1;
        }
    }
    f16x4 o0, o1;
    o0.x = (_Float16)acc0.x; o0.y = (_Float16)acc0.y;
    o0.z = (_Float16)acc0.z; o0.w = (_Float16)acc0.w;
    o1.x = (_Float16)acc1.x; o1.y = (_Float16)acc1.y;
    o1.z = (_Float16)acc1.z; o1.w = (_Float16)acc1.w;
    *(f16x4*)(z + (size_t)d0 * H + c) = o0;
    *(f16x4*)(z + (size_t)d1 * H + c) = o1;
}

// ---------------- fp16 MFMA GEMM: A and B via double-buffered swizzled LDS ----------
// tile 128x128, BK=32, 4 waves (2x2); one barrier/K-step; 4 blocks/CU.
// EPI 0: C16 = relu(bn(acc+bias))    EPI 1: C16 = that + res (fp16; res may alias C16)
template <int KDIM, int EPI>
__global__ __launch_bounds__(256, 4) void gemm_f16(
    const _Float16* __restrict__ A,
    const _Float16* __restrict__ BT,
    int Ncols,
    const float* __restrict__ bias, const float* __restrict__ bng,
    const float* __restrict__ bnb, const float* __restrict__ bnm,
    const float* __restrict__ bnv,
    _Float16* __restrict__ C16, const _Float16* __restrict__ res)
{
    __shared__ f16x8 As[2][512];               // [buf][row*4 + slot]
    __shared__ f16x8 Bs[2][512];

    const int tid = threadIdx.x;
    const int nt = Ncols >> 7;
    // XCD-bijective swizzle (m204)
    const int nwg = gridDim.x, orig = blockIdx.x;
    const int q = nwg >> 3, r = nwg & 7;
    const int xcd = orig & 7, rk = orig >> 3;
    const int wg = (xcd < r ? xcd * (q + 1) : r * (q + 1) + (xcd - r) * q) + rk;
    const int m0 = (wg / nt) * 128;
    const int n0 = (wg % nt) * 128;

    const int wid = tid >> 6, lane = tid & 63;
    const int wm = wid >> 1, wn = wid & 1;
    const int lrow = lane & 15, lgrp = lane >> 4;
    const int r0s = tid >> 2;                  // staging row 0..63 (and +64)
    const int kq  = tid & 3;                   // staging 16B slot
    const int sw0 = kq ^ ((r0s >> 1) & 3);
    const int sw1 = kq ^ (((r0s + 64) >> 1) & 3);

    f32x4 acc[4][4];
    const f32x4 zero4 = {0.0f, 0.0f, 0.0f, 0.0f};
    #pragma unroll
    for (int i = 0; i < 4; ++i)
        #pragma unroll
        for (int j = 0; j < 4; ++j) acc[i][j] = zero4;

    f16x8 a0, a1, b0, b1;
    #define SLOAD(K0)                                                             \
        a0 = *(const f16x8*)(A  + (size_t)(m0 + r0s) * KDIM + (K0) + kq * 8);     \
        a1 = *(const f16x8*)(A  + (size_t)(m0 + r0s + 64) * KDIM + (K0) + kq * 8);\
        b0 = *(const f16x8*)(BT + (size_t)(n0 + r0s) * KDIM + (K0) + kq * 8);     \
        b1 = *(const f16x8*)(BT + (size_t)(n0 + r0s + 64) * KDIM + (K0) + kq * 8);
    #define SWRITE(CUR)                                                           \
        As[CUR][r0s * 4 + sw0] = a0;  As[CUR][(r0s + 64) * 4 + sw1] = a1;         \
        Bs[CUR][r0s * 4 + sw0] = b0;  Bs[CUR][(r0s + 64) * 4 + sw1] = b1;

    SLOAD(0);
    int cur = 0;
    for (int k0 = 0; k0 < KDIM; k0 += 32) {
        SWRITE(cur);
        __syncthreads();                       // buf ready; also fences reads 2 iters back
        if (k0 + 32 < KDIM) { SLOAD(k0 + 32); }    // lands under the MFMAs below
        f16x8 af[4], bf[4];
        #pragma unroll
        for (int mi = 0; mi < 4; ++mi) {
            const int ar = wm * 64 + mi * 16 + lrow;
            af[mi] = As[cur][ar * 4 + (lgrp ^ ((ar >> 1) & 3))];
        }
        #pragma unroll
        for (int ni = 0; ni < 4; ++ni) {
            const int br = wn * 64 + ni * 16 + lrow;
            bf[ni] = Bs[cur][br * 4 + (lgrp ^ ((br >> 1) & 3))];
        }
        #pragma unroll
        for (int mi = 0; mi < 4; ++mi)
            #pragma unroll
            for (int ni = 0; ni < 4; ++ni)
                acc[mi][ni] = __builtin_amdgcn_mfma_f32_16x16x32_f16(af[mi], bf[ni], acc[mi][ni], 0, 0, 0);
        cur ^= 1;
    }
    #undef SLOAD
    #undef SWRITE

    float scl[4], shf[4];
    #pragma unroll
    for (int ni = 0; ni < 4; ++ni) {
        const int c = n0 + wn * 64 + ni * 16 + lrow;
        const float s = bng[c] * rsqrtf(bnv[c] + BN_EPS);
        scl[ni] = s;
        shf[ni] = s * (bias[c] - bnm[c]) + bnb[c];
    }
    #pragma unroll
    for (int mi = 0; mi < 4; ++mi)
        #pragma unroll
        for (int j = 0; j < 4; ++j) {
            const int row = m0 + wm * 64 + mi * 16 + lgrp * 4 + j;
            #pragma unroll
            for (int ni = 0; ni < 4; ++ni) {
                const int col = n0 + wn * 64 + ni * 16 + lrow;
                float v = fmaxf(scl[ni] * acc[mi][ni][j] + shf[ni], 0.0f);
                if (EPI == 1) v += (float)res[(size_t)row * Ncols + col];
                C16[(size_t)row * Ncols + col] = (_Float16)v;
            }
        }
}

// ---------------- pooling: mean + max per graph, fp16 out ----------------
__global__ __launch_bounds__(H) void pool_kernel(const _Float16* __restrict__ h16,
                                                 const int* __restrict__ batch,
                                                 _Float16* __restrict__ p16) {
    const int g = blockIdx.x;
    const int c = threadIdx.x;
    int lo, hi;
    {
        int a = 0, b = NA;
        while (a < b) { int mid = (a + b) >> 1; if (batch[mid] < g) a = mid + 1; else b = mid; }
        lo = a;
        b = NA;
        while (a < b) { int mid = (a + b) >> 1; if (batch[mid] < g + 1) a = mid + 1; else b = mid; }
        hi = a;
    }
    float sum = 0.0f, mx = -INFINITY;
    for (int n = lo; n < hi; ++n) {
        const float v = (float)h16[(size_t)n * H + c];
        sum += v;
        mx = fmaxf(mx, v);
    }
    const int cnt = hi - lo;
    const float mean = (cnt > 0) ? sum / (float)cnt : 0.0f;
    if (cnt == 0) mx = 0.0f;
    p16[(size_t)g * H2 + c] = (_Float16)mean;
    p16[(size_t)g * H2 + H + c] = (_Float16)mx;
}

// ---------------- final linear: out = q2 @ cw3 + cb3 ----------------
__global__ __launch_bounds__(64) void final_out(const _Float16* __restrict__ q2,
                                                const float* __restrict__ w,
                                                const float* __restrict__ b,
                                                float* __restrict__ out) {
    const int g = blockIdx.x;
    const int lane = threadIdx.x;
    float acc = (float)q2[(size_t)g * 128 + lane] * w[lane]
              + (float)q2[(size_t)g * 128 + 64 + lane] * w[64 + lane];
    #pragma unroll
    for (int off = 32; off > 0; off >>= 1) acc += __shfl_down(acc, off);
    if (lane == 0) out[g] = acc + b[0];
}

// ---------------- launch ----------------
extern "C" void kernel_launch(void* const* d_in, const int* in_sizes, int n_in,
                              void* d_out, int out_size, void* d_ws, size_t ws_size,
                              hipStream_t stream) {
    const float* x      = (const float*)d_in[0];
    const int*   ei     = (const int*)d_in[1];
    const int*   batch  = (const int*)d_in[2];
    const float* eattr  = (const float*)d_in[3];
    const float* enc_w  = (const float*)d_in[4];
    const float* enc_b  = (const float*)d_in[5];
    const float* bond_w = (const float*)d_in[6];
    const float* bond_b = (const float*)d_in[7];
    const float* eps    = (const float*)d_in[8];
    const float* w1     = (const float*)d_in[9];
    const float* b1     = (const float*)d_in[10];
    const float* ibn_g  = (const float*)d_in[11];
    const float* ibn_b  = (const float*)d_in[12];
    const float* ibn_m  = (const float*)d_in[13];
    const float* ibn_v  = (const float*)d_in[14];
    const float* w2     = (const float*)d_in[15];
    const float* b2     = (const float*)d_in[16];
    const float* obn_g  = (const float*)d_in[17];
    const float* obn_b  = (const float*)d_in[18];
    const float* obn_m  = (const float*)d_in[19];
    const float* obn_v  = (const float*)d_in[20];
    const float* cw1    = (const float*)d_in[21];
    const float* cb1    = (const float*)d_in[22];
    const float* c1g    = (const float*)d_in[23];
    const float* c1b    = (const float*)d_in[24];
    const float* c1m    = (const float*)d_in[25];
    const float* c1v    = (const float*)d_in[26];
    const float* cw2    = (const float*)d_in[27];
    const float* cb2    = (const float*)d_in[28];
    const float* c2g    = (const float*)d_in[29];
    const float* c2b    = (const float*)d_in[30];
    const float* c2m    = (const float*)d_in[31];
    const float* c2v    = (const float*)d_in[32];
    const float* cw3    = (const float*)d_in[33];
    const float* cb3    = (const float*)d_in[34];
    float* out = (float*)d_out;

    // ---- workspace layout (fp16 datapath) ----
    // [w1T|w2T|cw1T|cw2T fp16][csr ints][h16][z fp16][z1 fp16 chunk]
    const size_t WTE       = (size_t)NL * H * H2;            // 655360
    const size_t CW1E      = (size_t)H2 * H;                 // 131072
    const size_t CW2E      = (size_t)H * (H / 2);            // 32768
    const size_t wt_bytes  = (2 * WTE + CW1E + CW2E) * 2;
    const size_t csr_words = (size_t)3 * NA + 1 + 2 * (size_t)NE + 63;
    const size_t csr_bytes = csr_words * 4;
    const size_t h16_bytes = (size_t)NA * H * 2;             // 67 MB
    const size_t z_bytes   = (size_t)NA * H * 2;             // 67 MB
    const size_t z1_bytes  = (size_t)NA * H2 * 2;            // 134 MB
    const size_t need_full = wt_bytes + csr_bytes + h16_bytes + z_bytes + z1_bytes;

    char* buf;
    size_t buf_bytes;
    if (ws_size >= need_full) { buf = (char*)d_ws; buf_bytes = ws_size; }
    else if (g_buf)           { buf = g_buf;       buf_bytes = (size_t)320 * 1024 * 1024; }
    else                      { buf = (char*)d_ws; buf_bytes = ws_size; }

    _Float16* w1T  = (_Float16*)buf;
    _Float16* w2T  = w1T + WTE;
    _Float16* cw1T = w2T + WTE;
    _Float16* cw2T = cw1T + CW1E;
    int*  deg    = (int*)(buf + wt_bytes);
    int*  rowptr = deg + NA;
    int*  cursor = rowptr + NA + 1;
    int2* se     = (int2*)(cursor + NA);
    _Float16* h16 = (_Float16*)(buf + wt_bytes + csr_bytes);
    _Float16* z   = (_Float16*)((char*)h16 + h16_bytes);
    _Float16* z1c = (_Float16*)((char*)z + z_bytes);

    const size_t fixed_bytes = wt_bytes + csr_bytes + h16_bytes + z_bytes;
    const size_t avail_rows = (buf_bytes > fixed_bytes) ? (buf_bytes - fixed_bytes) / ((size_t)H2 * 2) : 0;
    int CH = (int)avail_rows;
    CH &= ~127;
    if (CH > NA) CH = NA;
    if (CH < 128) CH = 128;

    // classifier buffers alias z (dead after last layer's gemm1 consumed it)
    _Float16* p16 = z;                        // NG*H2
    _Float16* q1  = p16 + (size_t)NG * H2;    // NG*H
    _Float16* q2  = q1 + (size_t)NG * H;      // NG*(H/2)

    // ---- weight prep (transpose to fp16), once per call ----
    for (int l = 0; l < NL; ++l) {
        prep_w<<<dim3(H / 32, H2 / 32), 256, 0, stream>>>(
            w1 + (size_t)l * H * H2, H, H2, w1T + (size_t)l * H * H2);
        prep_w<<<dim3(H2 / 32, H / 32), 256, 0, stream>>>(
            w2 + (size_t)l * H2 * H, H2, H, w2T + (size_t)l * H2 * H);
    }
    prep_w<<<dim3(H2 / 32, H / 32), 256, 0, stream>>>(cw1, H2, H, cw1T);
    prep_w<<<dim3(H / 32, H / 64), 256, 0, stream>>>(cw2, H, H / 2, cw2T);

    // ---- CSR build (edges are layer-invariant) ----
    hipMemsetAsync(deg, 0, (size_t)NA * 4, stream);
    count_deg<<<NE / 256, 256, 0, stream>>>(ei, deg);
    scan_deg<<<1, 1024, 0, stream>>>(deg, rowptr, cursor);
    fill_elist<<<NE / 256, 256, 0, stream>>>(ei, cursor, se);

    encode_nodes<<<NA / 4, 256, 0, stream>>>(x, enc_w, enc_b, h16);

    for (int l = 0; l < NL; ++l) {
        gine_msg<<<NA / 8, 256, 0, stream>>>(h16, eattr, bond_w, bond_b, se, rowptr,
                                             eps, l, z);
        for (int r0 = 0; r0 < NA; r0 += CH) {
            const int CHc = (NA - r0 < CH) ? (NA - r0) : CH;
            gemm_f16<H, 0><<<(CHc / 128) * (H2 / 128), 256, 0, stream>>>(
                z + (size_t)r0 * H, w1T + (size_t)l * H * H2, H2,
                b1 + (size_t)l * H2, ibn_g + (size_t)l * H2, ibn_b + (size_t)l * H2,
                ibn_m + (size_t)l * H2, ibn_v + (size_t)l * H2,
                z1c, nullptr);
            gemm_f16<H2, 1><<<(CHc / 128) * (H / 128), 256, 0, stream>>>(
                z1c, w2T + (size_t)l * H2 * H, H,
                b2 + (size_t)l * H, obn_g + (size_t)l * H, obn_b + (size_t)l * H,
                obn_m + (size_t)l * H, obn_v + (size_t)l * H,
                h16 + (size_t)r0 * H, h16 + (size_t)r0 * H);
        }
    }

    pool_kernel<<<NG, H, 0, stream>>>(h16, batch, p16);
    // classifier layer 1: [NG,512] @ [512,256] -> q1
    gemm_f16<H2, 0><<<(NG / 128) * (H / 128), 256, 0, stream>>>(
        p16, cw1T, H, cb1, c1g, c1b, c1m, c1v, q1, nullptr);
    // classifier layer 2: [NG,256] @ [256,128] -> q2
    gemm_f16<H, 0><<<(NG / 128) * ((H / 2) / 128), 256, 0, stream>>>(
        q1, cw2T, H / 2, cb2, c2g, c2b, c2m, c2v, q2, nullptr);
    final_out<<<NG, 64, 0, stream>>>(q2, cw3, cb3, out);
}

// Round 10
// 1820.812 us; speedup vs baseline: 1.1366x; 1.1366x over previous
//
#include <hip/hip_runtime.h>
#include <math.h>

#define NA 131072   // atoms
#define NE 262144   // edges
#define NG 4096     // graphs
#define FN 30
#define FE 11
#define H  256
#define H2 512
#define NL 5
#define BN_EPS 1e-5f

typedef _Float16 f16x8 __attribute__((ext_vector_type(8)));
typedef _Float16 f16x4 __attribute__((ext_vector_type(4)));
typedef float f32x4 __attribute__((ext_vector_type(4)));

// ---- private fallback workspace, allocated ONCE at library load ----
static char* g_buf = nullptr;
__attribute__((constructor)) static void _alloc_private_ws() {
    void* p = nullptr;
    if (hipMalloc(&p, (size_t)424 * 1024 * 1024) == hipSuccess) g_buf = (char*)p;
}

// ---------------- weight prep: transpose to fp16 [N][K] ----------------
__global__ __launch_bounds__(256) void prep_w(const float* __restrict__ w, int K, int N,
                                              _Float16* __restrict__ hT) {
    __shared__ float t[32][33];
    const int k0 = blockIdx.x * 32, n0 = blockIdx.y * 32;
    const int tx = threadIdx.x & 31, ty = threadIdx.x >> 5;   // ty 0..7
    #pragma unroll
    for (int i = 0; i < 4; ++i)
        t[ty + i * 8][tx] = w[(size_t)(k0 + ty + i * 8) * N + n0 + tx];
    __syncthreads();
    #pragma unroll
    for (int i = 0; i < 4; ++i)
        hT[(size_t)(n0 + ty + i * 8) * K + k0 + tx] = (_Float16)t[tx][ty + i * 8];
}

// ---------------- node encoder: 4 rows/block, fp16 out ----------------
__global__ __launch_bounds__(256) void encode_nodes(const float* __restrict__ x,
                                                    const float* __restrict__ w,
                                                    const float* __restrict__ b,
                                                    _Float16* __restrict__ h16) {
    __shared__ float xs[4 * FN];
    const int t = threadIdx.x;
    const int blk = blockIdx.x;
    if (t < 4 * FN) xs[t] = x[(size_t)blk * 4 * FN + t];
    __syncthreads();
    const int rr = t >> 6;
    const int lane = t & 63;
    const int c = lane * 4;
    const float* xr = &xs[rr * FN];
    float4 acc = *(const float4*)(b + c);
    #pragma unroll
    for (int k = 0; k < FN; ++k) {
        const float a = xr[k];
        const float4 wv = *(const float4*)(w + (size_t)k * H + c);
        acc.x += a * wv.x; acc.y += a * wv.y; acc.z += a * wv.z; acc.w += a * wv.w;
    }
    f16x4 o;
    o.x = (_Float16)acc.x; o.y = (_Float16)acc.y;
    o.z = (_Float16)acc.z; o.w = (_Float16)acc.w;
    *(f16x4*)(h16 + (size_t)(blk * 4 + rr) * H + c) = o;
}

// ---------------- CSR build (once per call) ----------------
__global__ __launch_bounds__(256) void count_deg(const int* __restrict__ ei,
                                                 int* __restrict__ deg) {
    const int e = blockIdx.x * 256 + threadIdx.x;
    if (e < NE) atomicAdd(&deg[ei[NE + e]], 1);
}

__global__ __launch_bounds__(1024) void scan_deg(const int* __restrict__ deg,
                                                 int* __restrict__ rowptr,
                                                 int* __restrict__ cursor) {
    __shared__ int part[1024];
    const int t = threadIdx.x;
    const int base = t * 128;               // 1024*128 == NA
    int s = 0;
    #pragma unroll 8
    for (int i = 0; i < 128; ++i) s += deg[base + i];
    part[t] = s;
    __syncthreads();
    for (int off = 1; off < 1024; off <<= 1) {
        const int v = (t >= off) ? part[t - off] : 0;
        __syncthreads();
        part[t] += v;
        __syncthreads();
    }
    int run = (t == 0) ? 0 : part[t - 1];
    #pragma unroll 8
    for (int i = 0; i < 128; ++i) {
        rowptr[base + i] = run;
        cursor[base + i] = run;
        run += deg[base + i];
    }
    if (t == 1023) rowptr[NA] = run;        // == NE
}

__global__ __launch_bounds__(256) void fill_elist(const int* __restrict__ ei,
                                                  int* __restrict__ cursor,
                                                  int2* __restrict__ se) {
    const int e = blockIdx.x * 256 + threadIdx.x;
    if (e < NE) {
        const int src = ei[e];
        const int pos = atomicAdd(&cursor[ei[NE + e]], 1);
        se[pos] = make_int2(src, e);
    }
}

// ---- bond encoding, precomputed ONCE in CSR slot order (layer-invariant) ----
//      eb[t][c] = (eattr[se[t].y] @ bond_w + bond_b)[c]
__global__ __launch_bounds__(256) void build_ebond(const float* __restrict__ eattr,
                                                   const float* __restrict__ bond_w,
                                                   const float* __restrict__ bond_b,
                                                   const int2* __restrict__ se,
                                                   _Float16* __restrict__ eb) {
    const int t = blockIdx.x * 4 + (threadIdx.x >> 6);
    const int lane = threadIdx.x & 63;
    const int c = lane * 4;
    const int e = se[t].y;                      // wave-uniform
    float4 ev = *(const float4*)(bond_b + c);
    #pragma unroll
    for (int k = 0; k < FE; ++k) {
        const float a = eattr[(size_t)e * FE + k];
        const float4 wv = *(const float4*)(bond_w + (size_t)k * H + c);
        ev.x += a * wv.x; ev.y += a * wv.y; ev.z += a * wv.z; ev.w += a * wv.w;
    }
    f16x4 o;
    o.x = (_Float16)ev.x; o.y = (_Float16)ev.y;
    o.z = (_Float16)ev.z; o.w = (_Float16)ev.w;
    *(f16x4*)(eb + (size_t)t * H + c) = o;
}

// ---- GINE aggregation v4: wave-per-dst; sequential ebond stream + h16 gather ----
__global__ __launch_bounds__(256) void gine_msg(const _Float16* __restrict__ h16,
                                                const _Float16* __restrict__ eb,
                                                const int2* __restrict__ se,
                                                const int* __restrict__ rowptr,
                                                const float* __restrict__ eps, int l,
                                                _Float16* __restrict__ z) {
    const int dst = blockIdx.x * 4 + (threadIdx.x >> 6);
    const int lane = threadIdx.x & 63;
    const int c = lane * 4;
    const float sc = 1.0f + eps[l];
    const f16x4 hv = *(const f16x4*)(h16 + (size_t)dst * H + c);
    float4 acc;
    acc.x = sc * (float)hv.x; acc.y = sc * (float)hv.y;
    acc.z = sc * (float)hv.z; acc.w = sc * (float)hv.w;
    const int lo = rowptr[dst], hi = rowptr[dst + 1];
    for (int t = lo; t < hi; ++t) {
        const int src = se[t].x;                               // wave-uniform
        const f16x4 hs = *(const f16x4*)(h16 + (size_t)src * H + c);
        const f16x4 ev = *(const f16x4*)(eb + (size_t)t * H + c);
        acc.x += fmaxf((float)hs.x + (float)ev.x, 0.0f);
        acc.y += fmaxf((float)hs.y + (float)ev.y, 0.0f);
        acc.z += fmaxf((float)hs.z + (float)ev.z, 0.0f);
        acc.w += fmaxf((float)hs.w + (float)ev.w, 0.0f);
    }
    f16x4 o;
    o.x = (_Float16)acc.x; o.y = (_Float16)acc.y;
    o.z = (_Float16)acc.z; o.w = (_Float16)acc.w;
    *(f16x4*)(z + (size_t)dst * H + c) = o;
}

// ---------------- fp16 MFMA GEMM: A and B via double-buffered swizzled LDS ----------
// tile 128x128, BK=32, 4 waves (2x2); one barrier/K-step; 4 blocks/CU.
// EPI 0: C16 = relu(bn(acc+bias))    EPI 1: C16 = that + res (fp16; res may alias C16)
template <int KDIM, int EPI>
__global__ __launch_bounds__(256, 4) void gemm_f16(
    const _Float16* __restrict__ A,
    const _Float16* __restrict__ BT,
    int Ncols,
    const float* __restrict__ bias, const float* __restrict__ bng,
    const float* __restrict__ bnb, const float* __restrict__ bnm,
    const float* __restrict__ bnv,
    _Float16* __restrict__ C16, const _Float16* __restrict__ res)
{
    __shared__ f16x8 As[2][512];               // [buf][row*4 + slot]
    __shared__ f16x8 Bs[2][512];

    const int tid = threadIdx.x;
    const int nt = Ncols >> 7;
    // XCD-bijective swizzle (m204)
    const int nwg = gridDim.x, orig = blockIdx.x;
    const int q = nwg >> 3, r = nwg & 7;
    const int xcd = orig & 7, rk = orig >> 3;
    const int wg = (xcd < r ? xcd * (q + 1) : r * (q + 1) + (xcd - r) * q) + rk;
    const int m0 = (wg / nt) * 128;
    const int n0 = (wg % nt) * 128;

    const int wid = tid >> 6, lane = tid & 63;
    const int wm = wid >> 1, wn = wid & 1;
    const int lrow = lane & 15, lgrp = lane >> 4;
    const int r0s = tid >> 2;                  // staging row 0..63 (and +64)
    const int kq  = tid & 3;                   // staging 16B slot
    const int sw0 = kq ^ ((r0s >> 1) & 3);
    const int sw1 = kq ^ (((r0s + 64) >> 1) & 3);

    f32x4 acc[4][4];
    const f32x4 zero4 = {0.0f, 0.0f, 0.0f, 0.0f};
    #pragma unroll
    for (int i = 0; i < 4; ++i)
        #pragma unroll
        for (int j = 0; j < 4; ++j) acc[i][j] = zero4;

    f16x8 a0, a1, b0, b1;
    #define SLOAD(K0)                                                             \
        a0 = *(const f16x8*)(A  + (size_t)(m0 + r0s) * KDIM + (K0) + kq * 8);     \
        a1 = *(const f16x8*)(A  + (size_t)(m0 + r0s + 64) * KDIM + (K0) + kq * 8);\
        b0 = *(const f16x8*)(BT + (size_t)(n0 + r0s) * KDIM + (K0) + kq * 8);     \
        b1 = *(const f16x8*)(BT + (size_t)(n0 + r0s + 64) * KDIM + (K0) + kq * 8);
    #define SWRITE(CUR)                                                           \
        As[CUR][r0s * 4 + sw0] = a0;  As[CUR][(r0s + 64) * 4 + sw1] = a1;         \
        Bs[CUR][r0s * 4 + sw0] = b0;  Bs[CUR][(r0s + 64) * 4 + sw1] = b1;

    SLOAD(0);
    int cur = 0;
    for (int k0 = 0; k0 < KDIM; k0 += 32) {
        SWRITE(cur);
        __syncthreads();                       // buf ready; also fences reads 2 iters back
        if (k0 + 32 < KDIM) { SLOAD(k0 + 32); }    // lands under the MFMAs below
        f16x8 af[4], bf[4];
        #pragma unroll
        for (int mi = 0; mi < 4; ++mi) {
            const int ar = wm * 64 + mi * 16 + lrow;
            af[mi] = As[cur][ar * 4 + (lgrp ^ ((ar >> 1) & 3))];
        }
        #pragma unroll
        for (int ni = 0; ni < 4; ++ni) {
            const int br = wn * 64 + ni * 16 + lrow;
            bf[ni] = Bs[cur][br * 4 + (lgrp ^ ((br >> 1) & 3))];
        }
        #pragma unroll
        for (int mi = 0; mi < 4; ++mi)
            #pragma unroll
            for (int ni = 0; ni < 4; ++ni)
                acc[mi][ni] = __builtin_amdgcn_mfma_f32_16x16x32_f16(af[mi], bf[ni], acc[mi][ni], 0, 0, 0);
        cur ^= 1;
    }
    #undef SLOAD
    #undef SWRITE

    float scl[4], shf[4];
    #pragma unroll
    for (int ni = 0; ni < 4; ++ni) {
        const int c = n0 + wn * 64 + ni * 16 + lrow;
        const float s = bng[c] * rsqrtf(bnv[c] + BN_EPS);
        scl[ni] = s;
        shf[ni] = s * (bias[c] - bnm[c]) + bnb[c];
    }
    #pragma unroll
    for (int mi = 0; mi < 4; ++mi)
        #pragma unroll
        for (int j = 0; j < 4; ++j) {
            const int row = m0 + wm * 64 + mi * 16 + lgrp * 4 + j;
            #pragma unroll
            for (int ni = 0; ni < 4; ++ni) {
                const int col = n0 + wn * 64 + ni * 16 + lrow;
                float v = fmaxf(scl[ni] * acc[mi][ni][j] + shf[ni], 0.0f);
                if (EPI == 1) v += (float)res[(size_t)row * Ncols + col];
                C16[(size_t)row * Ncols + col] = (_Float16)v;
            }
        }
}

// ---------------- pooling: mean + max per graph, fp16 out ----------------
__global__ __launch_bounds__(H) void pool_kernel(const _Float16* __restrict__ h16,
                                                 const int* __restrict__ batch,
                                                 _Float16* __restrict__ p16) {
    const int g = blockIdx.x;
    const int c = threadIdx.x;
    int lo, hi;
    {
        int a = 0, b = NA;
        while (a < b) { int mid = (a + b) >> 1; if (batch[mid] < g) a = mid + 1; else b = mid; }
        lo = a;
        b = NA;
        while (a < b) { int mid = (a + b) >> 1; if (batch[mid] < g + 1) a = mid + 1; else b = mid; }
        hi = a;
    }
    float sum = 0.0f, mx = -INFINITY;
    for (int n = lo; n < hi; ++n) {
        const float v = (float)h16[(size_t)n * H + c];
        sum += v;
        mx = fmaxf(mx, v);
    }
    const int cnt = hi - lo;
    const float mean = (cnt > 0) ? sum / (float)cnt : 0.0f;
    if (cnt == 0) mx = 0.0f;
    p16[(size_t)g * H2 + c] = (_Float16)mean;
    p16[(size_t)g * H2 + H + c] = (_Float16)mx;
}

// ---------------- final linear: out = q2 @ cw3 + cb3 ----------------
__global__ __launch_bounds__(64) void final_out(const _Float16* __restrict__ q2,
                                                const float* __restrict__ w,
                                                const float* __restrict__ b,
                                                float* __restrict__ out) {
    const int g = blockIdx.x;
    const int lane = threadIdx.x;
    float acc = (float)q2[(size_t)g * 128 + lane] * w[lane]
              + (float)q2[(size_t)g * 128 + 64 + lane] * w[64 + lane];
    #pragma unroll
    for (int off = 32; off > 0; off >>= 1) acc += __shfl_down(acc, off);
    if (lane == 0) out[g] = acc + b[0];
}

// ---------------- launch ----------------
extern "C" void kernel_launch(void* const* d_in, const int* in_sizes, int n_in,
                              void* d_out, int out_size, void* d_ws, size_t ws_size,
                              hipStream_t stream) {
    const float* x      = (const float*)d_in[0];
    const int*   ei     = (const int*)d_in[1];
    const int*   batch  = (const int*)d_in[2];
    const float* eattr  = (const float*)d_in[3];
    const float* enc_w  = (const float*)d_in[4];
    const float* enc_b  = (const float*)d_in[5];
    const float* bond_w = (const float*)d_in[6];
    const float* bond_b = (const float*)d_in[7];
    const float* eps    = (const float*)d_in[8];
    const float* w1     = (const float*)d_in[9];
    const float* b1     = (const float*)d_in[10];
    const float* ibn_g  = (const float*)d_in[11];
    const float* ibn_b  = (const float*)d_in[12];
    const float* ibn_m  = (const float*)d_in[13];
    const float* ibn_v  = (const float*)d_in[14];
    const float* w2     = (const float*)d_in[15];
    const float* b2     = (const float*)d_in[16];
    const float* obn_g  = (const float*)d_in[17];
    const float* obn_b  = (const float*)d_in[18];
    const float* obn_m  = (const float*)d_in[19];
    const float* obn_v  = (const float*)d_in[20];
    const float* cw1    = (const float*)d_in[21];
    const float* cb1    = (const float*)d_in[22];
    const float* c1g    = (const float*)d_in[23];
    const float* c1b    = (const float*)d_in[24];
    const float* c1m    = (const float*)d_in[25];
    const float* c1v    = (const float*)d_in[26];
    const float* cw2    = (const float*)d_in[27];
    const float* cb2    = (const float*)d_in[28];
    const float* c2g    = (const float*)d_in[29];
    const float* c2b    = (const float*)d_in[30];
    const float* c2m    = (const float*)d_in[31];
    const float* c2v    = (const float*)d_in[32];
    const float* cw3    = (const float*)d_in[33];
    const float* cb3    = (const float*)d_in[34];
    float* out = (float*)d_out;

    // ---- workspace layout (fp16 datapath) ----
    // [w1T|w2T|cw1T|cw2T fp16][csr ints][ebond fp16 NE*H][h16][z fp16][z1 fp16 chunk]
    const size_t WTE       = (size_t)NL * H * H2;            // 655360
    const size_t CW1E      = (size_t)H2 * H;
    const size_t CW2E      = (size_t)H * (H / 2);
    const size_t wt_bytes  = (2 * WTE + CW1E + CW2E) * 2;
    const size_t csr_words = (size_t)3 * NA + 1 + 2 * (size_t)NE + 63;
    const size_t csr_bytes = csr_words * 4;
    const size_t eb_bytes  = (size_t)NE * H * 2;             // 134 MB
    const size_t h16_bytes = (size_t)NA * H * 2;             // 67 MB
    const size_t z_bytes   = (size_t)NA * H * 2;             // 67 MB
    const size_t z1_bytes  = (size_t)NA * H2 * 2;            // 134 MB
    const size_t need_full = wt_bytes + csr_bytes + eb_bytes + h16_bytes + z_bytes + z1_bytes;

    char* buf;
    size_t buf_bytes;
    if (ws_size >= need_full) { buf = (char*)d_ws; buf_bytes = ws_size; }
    else if (g_buf)           { buf = g_buf;       buf_bytes = (size_t)424 * 1024 * 1024; }
    else                      { buf = (char*)d_ws; buf_bytes = ws_size; }

    _Float16* w1T  = (_Float16*)buf;
    _Float16* w2T  = w1T + WTE;
    _Float16* cw1T = w2T + WTE;
    _Float16* cw2T = cw1T + CW1E;
    int*  deg    = (int*)(buf + wt_bytes);
    int*  rowptr = deg + NA;
    int*  cursor = rowptr + NA + 1;
    int2* se     = (int2*)(cursor + NA);
    _Float16* eb  = (_Float16*)(buf + wt_bytes + csr_bytes);
    _Float16* h16 = (_Float16*)((char*)eb + eb_bytes);
    _Float16* z   = (_Float16*)((char*)h16 + h16_bytes);
    _Float16* z1c = (_Float16*)((char*)z + z_bytes);

    const size_t fixed_bytes = wt_bytes + csr_bytes + eb_bytes + h16_bytes + z_bytes;
    const size_t avail_rows = (buf_bytes > fixed_bytes) ? (buf_bytes - fixed_bytes) / ((size_t)H2 * 2) : 0;
    int CH = (int)avail_rows;
    CH &= ~127;
    if (CH > NA) CH = NA;
    if (CH < 128) CH = 128;

    // classifier buffers alias z (dead after last layer's gemm1 consumed it)
    _Float16* p16 = z;                        // NG*H2
    _Float16* q1  = p16 + (size_t)NG * H2;    // NG*H
    _Float16* q2  = q1 + (size_t)NG * H;      // NG*(H/2)

    // ---- weight prep (transpose to fp16), once per call ----
    for (int l = 0; l < NL; ++l) {
        prep_w<<<dim3(H / 32, H2 / 32), 256, 0, stream>>>(
            w1 + (size_t)l * H * H2, H, H2, w1T + (size_t)l * H * H2);
        prep_w<<<dim3(H2 / 32, H / 32), 256, 0, stream>>>(
            w2 + (size_t)l * H2 * H, H2, H, w2T + (size_t)l * H2 * H);
    }
    prep_w<<<dim3(H2 / 32, H / 32), 256, 0, stream>>>(cw1, H2, H, cw1T);
    prep_w<<<dim3(H / 32, H / 64), 256, 0, stream>>>(cw2, H, H / 2, cw2T);

    // ---- CSR build (edges are layer-invariant) ----
    hipMemsetAsync(deg, 0, (size_t)NA * 4, stream);
    count_deg<<<NE / 256, 256, 0, stream>>>(ei, deg);
    scan_deg<<<1, 1024, 0, stream>>>(deg, rowptr, cursor);
    fill_elist<<<NE / 256, 256, 0, stream>>>(ei, cursor, se);
    build_ebond<<<NE / 4, 256, 0, stream>>>(eattr, bond_w, bond_b, se, eb);

    encode_nodes<<<NA / 4, 256, 0, stream>>>(x, enc_w, enc_b, h16);

    for (int l = 0; l < NL; ++l) {
        gine_msg<<<NA / 4, 256, 0, stream>>>(h16, eb, se, rowptr, eps, l, z);
        for (int r0 = 0; r0 < NA; r0 += CH) {
            const int CHc = (NA - r0 < CH) ? (NA - r0) : CH;
            gemm_f16<H, 0><<<(CHc / 128) * (H2 / 128), 256, 0, stream>>>(
                z + (size_t)r0 * H, w1T + (size_t)l * H * H2, H2,
                b1 + (size_t)l * H2, ibn_g + (size_t)l * H2, ibn_b + (size_t)l * H2,
                ibn_m + (size_t)l * H2, ibn_v + (size_t)l * H2,
                z1c, nullptr);
            gemm_f16<H2, 1><<<(CHc / 128) * (H / 128), 256, 0, stream>>>(
                z1c, w2T + (size_t)l * H2 * H, H,
                b2 + (size_t)l * H, obn_g + (size_t)l * H, obn_b + (size_t)l * H,
                obn_m + (size_t)l * H, obn_v + (size_t)l * H,
                h16 + (size_t)r0 * H, h16 + (size_t)r0 * H);
        }
    }

    pool_kernel<<<NG, H, 0, stream>>>(h16, batch, p16);
    // classifier layer 1: [NG,512] @ [512,256] -> q1
    gemm_f16<H2, 0><<<(NG / 128) * (H / 128), 256, 0, stream>>>(
        p16, cw1T, H, cb1, c1g, c1b, c1m, c1v, q1, nullptr);
    // classifier layer 2: [NG,256] @ [256,128] -> q2
    gemm_f16<H, 0><<<(NG / 128) * ((H / 2) / 128), 256, 0, stream>>>(
        q1, cw2T, H / 2, cb2, c2g, c2b, c2m, c2v, q2, nullptr);
    final_out<<<NG, 64, 0, stream>>>(q2, cw3, cb3, out);
}

// Round 11
// 1647.855 us; speedup vs baseline: 1.2559x; 1.1050x over previous
//
#include <hip/hip_runtime.h>
#include <math.h>

#define NA 131072   // atoms
#define NE 262144   // edges
#define NG 4096     // graphs
#define FN 30
#define FE 11
#define H  256
#define H2 512
#define NL 5
#define BN_EPS 1e-5f
#define KP 32       // padded K for encoder/bond GEMMs

typedef _Float16 f16x8 __attribute__((ext_vector_type(8)));
typedef _Float16 f16x4 __attribute__((ext_vector_type(4)));
typedef float f32x4 __attribute__((ext_vector_type(4)));

// ---- private fallback workspace, allocated ONCE at library load ----
static char* g_buf = nullptr;
__attribute__((constructor)) static void _alloc_private_ws() {
    void* p = nullptr;
    if (hipMalloc(&p, (size_t)456 * 1024 * 1024) == hipSuccess) g_buf = (char*)p;
}

// ---------------- weight prep: transpose to fp16 [N][K], layer via grid.z ----------
__global__ __launch_bounds__(256) void prep_w_all(const float* __restrict__ w, int K, int N,
                                                  _Float16* __restrict__ hT) {
    const float* wl = w + (size_t)blockIdx.z * K * N;
    _Float16* hTl = hT + (size_t)blockIdx.z * K * N;
    __shared__ float t[32][33];
    const int k0 = blockIdx.x * 32, n0 = blockIdx.y * 32;
    const int tx = threadIdx.x & 31, ty = threadIdx.x >> 5;   // ty 0..7
    #pragma unroll
    for (int i = 0; i < 4; ++i)
        t[ty + i * 8][tx] = wl[(size_t)(k0 + ty + i * 8) * N + n0 + tx];
    __syncthreads();
    #pragma unroll
    for (int i = 0; i < 4; ++i)
        hTl[(size_t)(n0 + ty + i * 8) * K + k0 + tx] = (_Float16)t[tx][ty + i * 8];
}

// ---- small-K weight pad+transpose: w [K_IN][H] fp32 -> wT [H][KP] fp16 (zero pad) ----
__global__ __launch_bounds__(256) void prep_wpad(const float* __restrict__ w, int K_IN,
                                                 _Float16* __restrict__ wT) {
    const int n = threadIdx.x;                 // one column per thread
    #pragma unroll
    for (int kk = 0; kk < KP / 8; ++kk) {
        f16x8 v;
        #pragma unroll
        for (int j = 0; j < 8; ++j) {
            const int k = kk * 8 + j;
            v[j] = (k < K_IN) ? (_Float16)w[(size_t)k * H + n] : (_Float16)0.0f;
        }
        *(f16x8*)(wT + (size_t)n * KP + kk * 8) = v;
    }
}

// ---- x [NA][FN] fp32 -> x16 [NA][KP] fp16 padded ----
__global__ __launch_bounds__(256) void prep_x16(const float* __restrict__ x,
                                                _Float16* __restrict__ x16) {
    const int row = blockIdx.x * 64 + (threadIdx.x >> 2);
    const int g = threadIdx.x & 3;
    f16x8 v;
    #pragma unroll
    for (int j = 0; j < 8; ++j) {
        const int c = g * 8 + j;
        v[j] = (c < FN) ? (_Float16)x[(size_t)row * FN + c] : (_Float16)0.0f;
    }
    *(f16x8*)(x16 + (size_t)row * KP + g * 8) = v;
}

// ---- eattr permuted to CSR slot order + padded: ea16[t] = pad(eattr[se[t].y]) ----
__global__ __launch_bounds__(256) void prep_ea16(const float* __restrict__ eattr,
                                                 const int2* __restrict__ se,
                                                 _Float16* __restrict__ ea16) {
    const int t = blockIdx.x * 64 + (threadIdx.x >> 2);
    const int g = threadIdx.x & 3;
    const int e = se[t].y;
    f16x8 v;
    #pragma unroll
    for (int j = 0; j < 8; ++j) {
        const int c = g * 8 + j;
        v[j] = (c < FE) ? (_Float16)eattr[(size_t)e * FE + c] : (_Float16)0.0f;
    }
    *(f16x8*)(ea16 + (size_t)t * KP + g * 8) = v;
}

// ---------------- CSR build (once per call) ----------------
__global__ __launch_bounds__(256) void count_deg(const int* __restrict__ ei,
                                                 int* __restrict__ deg) {
    const int e = blockIdx.x * 256 + threadIdx.x;
    if (e < NE) atomicAdd(&deg[ei[NE + e]], 1);
}

__global__ __launch_bounds__(1024) void scan_deg(const int* __restrict__ deg,
                                                 int* __restrict__ rowptr,
                                                 int* __restrict__ cursor) {
    __shared__ int part[1024];
    const int t = threadIdx.x;
    const int base = t * 128;               // 1024*128 == NA
    int s = 0;
    #pragma unroll 8
    for (int i = 0; i < 128; ++i) s += deg[base + i];
    part[t] = s;
    __syncthreads();
    for (int off = 1; off < 1024; off <<= 1) {
        const int v = (t >= off) ? part[t - off] : 0;
        __syncthreads();
        part[t] += v;
        __syncthreads();
    }
    int run = (t == 0) ? 0 : part[t - 1];
    #pragma unroll 8
    for (int i = 0; i < 128; ++i) {
        rowptr[base + i] = run;
        cursor[base + i] = run;
        run += deg[base + i];
    }
    if (t == 1023) rowptr[NA] = run;        // == NE
}

__global__ __launch_bounds__(256) void fill_elist(const int* __restrict__ ei,
                                                  int* __restrict__ cursor,
                                                  int2* __restrict__ se) {
    const int e = blockIdx.x * 256 + threadIdx.x;
    if (e < NE) {
        const int src = ei[e];
        const int pos = atomicAdd(&cursor[ei[NE + e]], 1);
        se[pos] = make_int2(src, e);
    }
}

// ---- GINE aggregation: wave-per-dst; sequential ebond stream + h16 gather ----
__global__ __launch_bounds__(256) void gine_msg(const _Float16* __restrict__ h16,
                                                const _Float16* __restrict__ eb,
                                                const int2* __restrict__ se,
                                                const int* __restrict__ rowptr,
                                                const float* __restrict__ eps, int l,
                                                _Float16* __restrict__ z) {
    const int dst = blockIdx.x * 4 + (threadIdx.x >> 6);
    const int lane = threadIdx.x & 63;
    const int c = lane * 4;
    const float sc = 1.0f + eps[l];
    const f16x4 hv = *(const f16x4*)(h16 + (size_t)dst * H + c);
    float4 acc;
    acc.x = sc * (float)hv.x; acc.y = sc * (float)hv.y;
    acc.z = sc * (float)hv.z; acc.w = sc * (float)hv.w;
    const int lo = rowptr[dst], hi = rowptr[dst + 1];
    for (int t = lo; t < hi; ++t) {
        const int src = se[t].x;                               // wave-uniform
        const f16x4 hs = *(const f16x4*)(h16 + (size_t)src * H + c);
        const f16x4 ev = *(const f16x4*)(eb + (size_t)t * H + c);
        acc.x += fmaxf((float)hs.x + (float)ev.x, 0.0f);
        acc.y += fmaxf((float)hs.y + (float)ev.y, 0.0f);
        acc.z += fmaxf((float)hs.z + (float)ev.z, 0.0f);
        acc.w += fmaxf((float)hs.w + (float)ev.w, 0.0f);
    }
    f16x4 o;
    o.x = (_Float16)acc.x; o.y = (_Float16)acc.y;
    o.z = (_Float16)acc.z; o.w = (_Float16)acc.w;
    *(f16x4*)(z + (size_t)dst * H + c) = o;
}

// ---------------- fp16 MFMA GEMM: A and B via double-buffered swizzled LDS ----------
// tile 128x128, BK=32, 4 waves (2x2); one barrier/K-step; 4 blocks/CU.
// EPI 0: relu(bn(acc+bias))  EPI 1: that + res (may alias C16)  EPI 2: acc+bias only
template <int KDIM, int EPI>
__global__ __launch_bounds__(256, 4) void gemm_f16(
    const _Float16* __restrict__ A,
    const _Float16* __restrict__ BT,
    int Ncols,
    const float* __restrict__ bias, const float* __restrict__ bng,
    const float* __restrict__ bnb, const float* __restrict__ bnm,
    const float* __restrict__ bnv,
    _Float16* __restrict__ C16, const _Float16* __restrict__ res)
{
    __shared__ f16x8 As[2][512];               // [buf][row*4 + slot]
    __shared__ f16x8 Bs[2][512];

    const int tid = threadIdx.x;
    const int nt = Ncols >> 7;
    // XCD-bijective swizzle (m204)
    const int nwg = gridDim.x, orig = blockIdx.x;
    const int q = nwg >> 3, r = nwg & 7;
    const int xcd = orig & 7, rk = orig >> 3;
    const int wg = (xcd < r ? xcd * (q + 1) : r * (q + 1) + (xcd - r) * q) + rk;
    const int m0 = (wg / nt) * 128;
    const int n0 = (wg % nt) * 128;

    const int wid = tid >> 6, lane = tid & 63;
    const int wm = wid >> 1, wn = wid & 1;
    const int lrow = lane & 15, lgrp = lane >> 4;
    const int r0s = tid >> 2;                  // staging row 0..63 (and +64)
    const int kq  = tid & 3;                   // staging 16B slot
    const int sw0 = kq ^ ((r0s >> 1) & 3);
    const int sw1 = kq ^ (((r0s + 64) >> 1) & 3);

    f32x4 acc[4][4];
    const f32x4 zero4 = {0.0f, 0.0f, 0.0f, 0.0f};
    #pragma unroll
    for (int i = 0; i < 4; ++i)
        #pragma unroll
        for (int j = 0; j < 4; ++j) acc[i][j] = zero4;

    f16x8 a0, a1, b0, b1;
    #define SLOAD(K0)                                                             \
        a0 = *(const f16x8*)(A  + (size_t)(m0 + r0s) * KDIM + (K0) + kq * 8);     \
        a1 = *(const f16x8*)(A  + (size_t)(m0 + r0s + 64) * KDIM + (K0) + kq * 8);\
        b0 = *(const f16x8*)(BT + (size_t)(n0 + r0s) * KDIM + (K0) + kq * 8);     \
        b1 = *(const f16x8*)(BT + (size_t)(n0 + r0s + 64) * KDIM + (K0) + kq * 8);
    #define SWRITE(CUR)                                                           \
        As[CUR][r0s * 4 + sw0] = a0;  As[CUR][(r0s + 64) * 4 + sw1] = a1;         \
        Bs[CUR][r0s * 4 + sw0] = b0;  Bs[CUR][(r0s + 64) * 4 + sw1] = b1;

    SLOAD(0);
    int cur = 0;
    for (int k0 = 0; k0 < KDIM; k0 += 32) {
        SWRITE(cur);
        __syncthreads();                       // buf ready; also fences reads 2 iters back
        if (k0 + 32 < KDIM) { SLOAD(k0 + 32); }    // lands under the MFMAs below
        f16x8 af[4], bf[4];
        #pragma unroll
        for (int mi = 0; mi < 4; ++mi) {
            const int ar = wm * 64 + mi * 16 + lrow;
            af[mi] = As[cur][ar * 4 + (lgrp ^ ((ar >> 1) & 3))];
        }
        #pragma unroll
        for (int ni = 0; ni < 4; ++ni) {
            const int br = wn * 64 + ni * 16 + lrow;
            bf[ni] = Bs[cur][br * 4 + (lgrp ^ ((br >> 1) & 3))];
        }
        #pragma unroll
        for (int mi = 0; mi < 4; ++mi)
            #pragma unroll
            for (int ni = 0; ni < 4; ++ni)
                acc[mi][ni] = __builtin_amdgcn_mfma_f32_16x16x32_f16(af[mi], bf[ni], acc[mi][ni], 0, 0, 0);
        cur ^= 1;
    }
    #undef SLOAD
    #undef SWRITE

    float scl[4], shf[4];
    #pragma unroll
    for (int ni = 0; ni < 4; ++ni) {
        const int c = n0 + wn * 64 + ni * 16 + lrow;
        if (EPI == 2) {
            scl[ni] = 1.0f;
            shf[ni] = bias[c];
        } else {
            const float s = bng[c] * rsqrtf(bnv[c] + BN_EPS);
            scl[ni] = s;
            shf[ni] = s * (bias[c] - bnm[c]) + bnb[c];
        }
    }
    #pragma unroll
    for (int mi = 0; mi < 4; ++mi)
        #pragma unroll
        for (int j = 0; j < 4; ++j) {
            const int row = m0 + wm * 64 + mi * 16 + lgrp * 4 + j;
            #pragma unroll
            for (int ni = 0; ni < 4; ++ni) {
                const int col = n0 + wn * 64 + ni * 16 + lrow;
                float v = scl[ni] * acc[mi][ni][j] + shf[ni];
                if (EPI != 2) v = fmaxf(v, 0.0f);
                if (EPI == 1) v += (float)res[(size_t)row * Ncols + col];
                C16[(size_t)row * Ncols + col] = (_Float16)v;
            }
        }
}

// ---------------- pooling: mean + max per graph, fp16 out ----------------
__global__ __launch_bounds__(H) void pool_kernel(const _Float16* __restrict__ h16,
                                                 const int* __restrict__ batch,
                                                 _Float16* __restrict__ p16) {
    const int g = blockIdx.x;
    const int c = threadIdx.x;
    int lo, hi;
    {
        int a = 0, b = NA;
        while (a < b) { int mid = (a + b) >> 1; if (batch[mid] < g) a = mid + 1; else b = mid; }
        lo = a;
        b = NA;
        while (a < b) { int mid = (a + b) >> 1; if (batch[mid] < g + 1) a = mid + 1; else b = mid; }
        hi = a;
    }
    float sum = 0.0f, mx = -INFINITY;
    for (int n = lo; n < hi; ++n) {
        const float v = (float)h16[(size_t)n * H + c];
        sum += v;
        mx = fmaxf(mx, v);
    }
    const int cnt = hi - lo;
    const float mean = (cnt > 0) ? sum / (float)cnt : 0.0f;
    if (cnt == 0) mx = 0.0f;
    p16[(size_t)g * H2 + c] = (_Float16)mean;
    p16[(size_t)g * H2 + H + c] = (_Float16)mx;
}

// ---------------- final linear: out = q2 @ cw3 + cb3 ----------------
__global__ __launch_bounds__(64) void final_out(const _Float16* __restrict__ q2,
                                                const float* __restrict__ w,
                                                const float* __restrict__ b,
                                                float* __restrict__ out) {
    const int g = blockIdx.x;
    const int lane = threadIdx.x;
    float acc = (float)q2[(size_t)g * 128 + lane] * w[lane]
              + (float)q2[(size_t)g * 128 + 64 + lane] * w[64 + lane];
    #pragma unroll
    for (int off = 32; off > 0; off >>= 1) acc += __shfl_down(acc, off);
    if (lane == 0) out[g] = acc + b[0];
}

// ---------------- launch ----------------
extern "C" void kernel_launch(void* const* d_in, const int* in_sizes, int n_in,
                              void* d_out, int out_size, void* d_ws, size_t ws_size,
                              hipStream_t stream) {
    const float* x      = (const float*)d_in[0];
    const int*   ei     = (const int*)d_in[1];
    const int*   batch  = (const int*)d_in[2];
    const float* eattr  = (const float*)d_in[3];
    const float* enc_w  = (const float*)d_in[4];
    const float* enc_b  = (const float*)d_in[5];
    const float* bond_w = (const float*)d_in[6];
    const float* bond_b = (const float*)d_in[7];
    const float* eps    = (const float*)d_in[8];
    const float* w1     = (const float*)d_in[9];
    const float* b1     = (const float*)d_in[10];
    const float* ibn_g  = (const float*)d_in[11];
    const float* ibn_b  = (const float*)d_in[12];
    const float* ibn_m  = (const float*)d_in[13];
    const float* ibn_v  = (const float*)d_in[14];
    const float* w2     = (const float*)d_in[15];
    const float* b2     = (const float*)d_in[16];
    const float* obn_g  = (const float*)d_in[17];
    const float* obn_b  = (const float*)d_in[18];
    const float* obn_m  = (const float*)d_in[19];
    const float* obn_v  = (const float*)d_in[20];
    const float* cw1    = (const float*)d_in[21];
    const float* cb1    = (const float*)d_in[22];
    const float* c1g    = (const float*)d_in[23];
    const float* c1b    = (const float*)d_in[24];
    const float* c1m    = (const float*)d_in[25];
    const float* c1v    = (const float*)d_in[26];
    const float* cw2    = (const float*)d_in[27];
    const float* cb2    = (const float*)d_in[28];
    const float* c2g    = (const float*)d_in[29];
    const float* c2b    = (const float*)d_in[30];
    const float* c2m    = (const float*)d_in[31];
    const float* c2v    = (const float*)d_in[32];
    const float* cw3    = (const float*)d_in[33];
    const float* cb3    = (const float*)d_in[34];
    float* out = (float*)d_out;

    // ---- workspace layout (fp16 datapath) ----
    // [w1T|w2T|cw1T|cw2T|enc_wT|bond_wT fp16][csr ints][eb NE*H][h16][z][z1][x16][ea16]
    const size_t WTE       = (size_t)NL * H * H2;
    const size_t CW1E      = (size_t)H2 * H;
    const size_t CW2E      = (size_t)H * (H / 2);
    const size_t EWE       = (size_t)H * KP;                 // enc_wT
    const size_t BWE       = (size_t)H * KP;                 // bond_wT
    const size_t wt_bytes  = (2 * WTE + CW1E + CW2E + EWE + BWE) * 2;
    const size_t csr_words = (size_t)3 * NA + 1 + 2 * (size_t)NE + 63;
    const size_t csr_bytes = csr_words * 4;
    const size_t eb_bytes  = (size_t)NE * H * 2;             // 134 MB
    const size_t h16_bytes = (size_t)NA * H * 2;             // 67 MB
    const size_t z_bytes   = (size_t)NA * H * 2;             // 67 MB
    const size_t z1_bytes  = (size_t)NA * H2 * 2;            // 134 MB
    const size_t x16_bytes = (size_t)NA * KP * 2;            // 8.4 MB
    const size_t ea_bytes  = (size_t)NE * KP * 2;            // 16.8 MB
    const size_t need_full = wt_bytes + csr_bytes + eb_bytes + h16_bytes + z_bytes
                           + z1_bytes + x16_bytes + ea_bytes;

    char* buf;
    size_t buf_bytes;
    if (ws_size >= need_full) { buf = (char*)d_ws; buf_bytes = ws_size; }
    else if (g_buf)           { buf = g_buf;       buf_bytes = (size_t)456 * 1024 * 1024; }
    else                      { buf = (char*)d_ws; buf_bytes = ws_size; }

    _Float16* w1T  = (_Float16*)buf;
    _Float16* w2T  = w1T + WTE;
    _Float16* cw1T = w2T + WTE;
    _Float16* cw2T = cw1T + CW1E;
    _Float16* encT = cw2T + CW2E;
    _Float16* bndT = encT + EWE;
    int*  deg    = (int*)(buf + wt_bytes);
    int*  rowptr = deg + NA;
    int*  cursor = rowptr + NA + 1;
    int2* se     = (int2*)(cursor + NA);
    _Float16* eb  = (_Float16*)(buf + wt_bytes + csr_bytes);
    _Float16* h16 = (_Float16*)((char*)eb + eb_bytes);
    _Float16* z   = (_Float16*)((char*)h16 + h16_bytes);
    _Float16* z1c = (_Float16*)((char*)z + z_bytes);
    // x16/ea16 live AFTER the full z1 region (sized for the d_ws full-layout case);
    // in the g_buf case buf_bytes covers need_full so they fit too.
    _Float16* x16  = (_Float16*)((char*)z1c + z1_bytes);
    _Float16* ea16 = (_Float16*)((char*)x16 + x16_bytes);

    const size_t fixed_bytes = wt_bytes + csr_bytes + eb_bytes + h16_bytes + z_bytes
                             + x16_bytes + ea_bytes;
    const size_t avail_rows = (buf_bytes > fixed_bytes) ? (buf_bytes - fixed_bytes) / ((size_t)H2 * 2) : 0;
    int CH = (int)avail_rows;
    CH &= ~127;
    if (CH > NA) CH = NA;
    if (CH < 128) CH = 128;

    // classifier buffers alias z (dead after last layer's gemm1 consumed it)
    _Float16* p16 = z;                        // NG*H2
    _Float16* q1  = p16 + (size_t)NG * H2;    // NG*H
    _Float16* q2  = q1 + (size_t)NG * H;      // NG*(H/2)

    // ---- weight prep (transpose to fp16), once per call ----
    prep_w_all<<<dim3(H / 32, H2 / 32, NL), 256, 0, stream>>>(w1, H, H2, w1T);
    prep_w_all<<<dim3(H2 / 32, H / 32, NL), 256, 0, stream>>>(w2, H2, H, w2T);
    prep_w_all<<<dim3(H2 / 32, H / 32, 1), 256, 0, stream>>>(cw1, H2, H, cw1T);
    prep_w_all<<<dim3(H / 32, H / 64, 1), 256, 0, stream>>>(cw2, H, H / 2, cw2T);
    prep_wpad<<<1, 256, 0, stream>>>(enc_w, FN, encT);
    prep_wpad<<<1, 256, 0, stream>>>(bond_w, FE, bndT);

    // ---- CSR build (edges are layer-invariant) ----
    hipMemsetAsync(deg, 0, (size_t)NA * 4, stream);
    count_deg<<<NE / 256, 256, 0, stream>>>(ei, deg);
    scan_deg<<<1, 1024, 0, stream>>>(deg, rowptr, cursor);
    fill_elist<<<NE / 256, 256, 0, stream>>>(ei, cursor, se);

    // ---- inputs to fp16 (padded K=32) ----
    prep_x16<<<NA / 64, 256, 0, stream>>>(x, x16);
    prep_ea16<<<NE / 64, 256, 0, stream>>>(eattr, se, ea16);

    // ---- encoder + bond encoding as MFMA GEMMs (EPI=2: bias only) ----
    gemm_f16<KP, 2><<<(NA / 128) * (H / 128), 256, 0, stream>>>(
        x16, encT, H, enc_b, nullptr, nullptr, nullptr, nullptr, h16, nullptr);
    gemm_f16<KP, 2><<<(NE / 128) * (H / 128), 256, 0, stream>>>(
        ea16, bndT, H, bond_b, nullptr, nullptr, nullptr, nullptr, eb, nullptr);

    for (int l = 0; l < NL; ++l) {
        gine_msg<<<NA / 4, 256, 0, stream>>>(h16, eb, se, rowptr, eps, l, z);
        for (int r0 = 0; r0 < NA; r0 += CH) {
            const int CHc = (NA - r0 < CH) ? (NA - r0) : CH;
            gemm_f16<H, 0><<<(CHc / 128) * (H2 / 128), 256, 0, stream>>>(
                z + (size_t)r0 * H, w1T + (size_t)l * H * H2, H2,
                b1 + (size_t)l * H2, ibn_g + (size_t)l * H2, ibn_b + (size_t)l * H2,
                ibn_m + (size_t)l * H2, ibn_v + (size_t)l * H2,
                z1c, nullptr);
            gemm_f16<H2, 1><<<(CHc / 128) * (H / 128), 256, 0, stream>>>(
                z1c, w2T + (size_t)l * H2 * H, H,
                b2 + (size_t)l * H, obn_g + (size_t)l * H, obn_b + (size_t)l * H,
                obn_m + (size_t)l * H, obn_v + (size_t)l * H,
                h16 + (size_t)r0 * H, h16 + (size_t)r0 * H);
        }
    }

    pool_kernel<<<NG, H, 0, stream>>>(h16, batch, p16);
    // classifier layer 1: [NG,512] @ [512,256] -> q1
    gemm_f16<H2, 0><<<(NG / 128) * (H / 128), 256, 0, stream>>>(
        p16, cw1T, H, cb1, c1g, c1b, c1m, c1v, q1, nullptr);
    // classifier layer 2: [NG,256] @ [256,128] -> q2
    gemm_f16<H, 0><<<(NG / 128) * ((H / 2) / 128), 256, 0, stream>>>(
        q1, cw2T, H / 2, cb2, c2g, c2b, c2m, c2v, q2, nullptr);
    final_out<<<NG, 64, 0, stream>>>(q2, cw3, cb3, out);
}

// Round 12
// 1288.069 us; speedup vs baseline: 1.6067x; 1.2793x over previous
//
#include <hip/hip_runtime.h>
#include <math.h>

#define NA 131072   // atoms
#define NE 262144   // edges
#define NG 4096     // graphs
#define FN 30
#define FE 11
#define H  256
#define H2 512
#define NL 5
#define BN_EPS 1e-5f
#define KP 32       // padded K for encoder/bond GEMMs

typedef _Float16 f16x8 __attribute__((ext_vector_type(8)));
typedef _Float16 f16x4 __attribute__((ext_vector_type(4)));
typedef float f32x4 __attribute__((ext_vector_type(4)));

// ---- private fallback workspace, allocated ONCE at library load ----
static char* g_buf = nullptr;
__attribute__((constructor)) static void _alloc_private_ws() {
    void* p = nullptr;
    if (hipMalloc(&p, (size_t)320 * 1024 * 1024) == hipSuccess) g_buf = (char*)p;
}

// ---------------- weight prep: transpose to fp16 [N][K], layer via grid.z ----------
__global__ __launch_bounds__(256) void prep_w_all(const float* __restrict__ w, int K, int N,
                                                  _Float16* __restrict__ hT) {
    const float* wl = w + (size_t)blockIdx.z * K * N;
    _Float16* hTl = hT + (size_t)blockIdx.z * K * N;
    __shared__ float t[32][33];
    const int k0 = blockIdx.x * 32, n0 = blockIdx.y * 32;
    const int tx = threadIdx.x & 31, ty = threadIdx.x >> 5;   // ty 0..7
    #pragma unroll
    for (int i = 0; i < 4; ++i)
        t[ty + i * 8][tx] = wl[(size_t)(k0 + ty + i * 8) * N + n0 + tx];
    __syncthreads();
    #pragma unroll
    for (int i = 0; i < 4; ++i)
        hTl[(size_t)(n0 + ty + i * 8) * K + k0 + tx] = (_Float16)t[tx][ty + i * 8];
}

// ---- small-K weight pad+transpose: w [K_IN][H] fp32 -> wT [H][KP] fp16 (zero pad) ----
__global__ __launch_bounds__(256) void prep_wpad(const float* __restrict__ w, int K_IN,
                                                 _Float16* __restrict__ wT) {
    const int n = threadIdx.x;
    #pragma unroll
    for (int kk = 0; kk < KP / 8; ++kk) {
        f16x8 v;
        #pragma unroll
        for (int j = 0; j < 8; ++j) {
            const int k = kk * 8 + j;
            v[j] = (k < K_IN) ? (_Float16)w[(size_t)k * H + n] : (_Float16)0.0f;
        }
        *(f16x8*)(wT + (size_t)n * KP + kk * 8) = v;
    }
}

// ---- x [NA][FN] fp32 -> x16 [NA][KP] fp16 padded ----
__global__ __launch_bounds__(256) void prep_x16(const float* __restrict__ x,
                                                _Float16* __restrict__ x16) {
    const int row = blockIdx.x * 64 + (threadIdx.x >> 2);
    const int g = threadIdx.x & 3;
    f16x8 v;
    #pragma unroll
    for (int j = 0; j < 8; ++j) {
        const int c = g * 8 + j;
        v[j] = (c < FN) ? (_Float16)x[(size_t)row * FN + c] : (_Float16)0.0f;
    }
    *(f16x8*)(x16 + (size_t)row * KP + g * 8) = v;
}

// ---- eattr permuted to CSR slot order + padded ----
__global__ __launch_bounds__(256) void prep_ea16(const float* __restrict__ eattr,
                                                 const int2* __restrict__ se,
                                                 _Float16* __restrict__ ea16) {
    const int t = blockIdx.x * 64 + (threadIdx.x >> 2);
    const int g = threadIdx.x & 3;
    const int e = se[t].y;
    f16x8 v;
    #pragma unroll
    for (int j = 0; j < 8; ++j) {
        const int c = g * 8 + j;
        v[j] = (c < FE) ? (_Float16)eattr[(size_t)e * FE + c] : (_Float16)0.0f;
    }
    *(f16x8*)(ea16 + (size_t)t * KP + g * 8) = v;
}

// ---------------- CSR build (once per call) ----------------
__global__ __launch_bounds__(256) void count_deg(const int* __restrict__ ei,
                                                 int* __restrict__ deg) {
    const int e = blockIdx.x * 256 + threadIdx.x;
    if (e < NE) atomicAdd(&deg[ei[NE + e]], 1);
}

__global__ __launch_bounds__(1024) void scan_deg(const int* __restrict__ deg,
                                                 int* __restrict__ rowptr,
                                                 int* __restrict__ cursor) {
    __shared__ int part[1024];
    const int t = threadIdx.x;
    const int base = t * 128;               // 1024*128 == NA
    int s = 0;
    #pragma unroll 8
    for (int i = 0; i < 128; ++i) s += deg[base + i];
    part[t] = s;
    __syncthreads();
    for (int off = 1; off < 1024; off <<= 1) {
        const int v = (t >= off) ? part[t - off] : 0;
        __syncthreads();
        part[t] += v;
        __syncthreads();
    }
    int run = (t == 0) ? 0 : part[t - 1];
    #pragma unroll 8
    for (int i = 0; i < 128; ++i) {
        rowptr[base + i] = run;
        cursor[base + i] = run;
        run += deg[base + i];
    }
    if (t == 1023) rowptr[NA] = run;        // == NE
}

__global__ __launch_bounds__(256) void fill_elist(const int* __restrict__ ei,
                                                  int* __restrict__ cursor,
                                                  int2* __restrict__ se) {
    const int e = blockIdx.x * 256 + threadIdx.x;
    if (e < NE) {
        const int src = ei[e];
        const int pos = atomicAdd(&cursor[ei[NE + e]], 1);
        se[pos] = make_int2(src, e);
    }
}

// ---- GINE aggregation: wave-per-dst; sequential ebond stream + h16 gather ----
__global__ __launch_bounds__(256) void gine_msg(const _Float16* __restrict__ h16,
                                                const _Float16* __restrict__ eb,
                                                const int2* __restrict__ se,
                                                const int* __restrict__ rowptr,
                                                const float* __restrict__ eps, int l,
                                                _Float16* __restrict__ z) {
    const int dst = blockIdx.x * 4 + (threadIdx.x >> 6);
    const int lane = threadIdx.x & 63;
    const int c = lane * 4;
    const float sc = 1.0f + eps[l];
    const f16x4 hv = *(const f16x4*)(h16 + (size_t)dst * H + c);
    float4 acc;
    acc.x = sc * (float)hv.x; acc.y = sc * (float)hv.y;
    acc.z = sc * (float)hv.z; acc.w = sc * (float)hv.w;
    const int lo = rowptr[dst], hi = rowptr[dst + 1];
    for (int t = lo; t < hi; ++t) {
        const int src = se[t].x;                               // wave-uniform
        const f16x4 hs = *(const f16x4*)(h16 + (size_t)src * H + c);
        const f16x4 ev = *(const f16x4*)(eb + (size_t)t * H + c);
        acc.x += fmaxf((float)hs.x + (float)ev.x, 0.0f);
        acc.y += fmaxf((float)hs.y + (float)ev.y, 0.0f);
        acc.z += fmaxf((float)hs.z + (float)ev.z, 0.0f);
        acc.w += fmaxf((float)hs.w + (float)ev.w, 0.0f);
    }
    f16x4 o;
    o.x = (_Float16)acc.x; o.y = (_Float16)acc.y;
    o.z = (_Float16)acc.z; o.w = (_Float16)acc.w;
    *(f16x4*)(z + (size_t)dst * H + c) = o;
}

// ================= fused per-layer MLP: h16 = relu(bn2(relu(bn1(z@w1))@w2)) + h16 ====
// 64-row M-tile per block; 512 thr = 8 waves (2x4), wave tile 32x64.
// Phase 1 (2 col-halves of 256): z1 -> LDS Z1[64][520] (1040B stride: 16B-aligned,
// 4-bank shift/row). Phase 2: A from Z1, B (w2T) staged. LDS total 107 KB.
__global__ __launch_bounds__(512, 2) void fused_mlp(
    const _Float16* __restrict__ Az,      // z [NA][256]
    const _Float16* __restrict__ W1T,     // [512][256]
    const _Float16* __restrict__ W2T,     // [256][512]
    const float* __restrict__ b1l, const float* __restrict__ ig,
    const float* __restrict__ ib, const float* __restrict__ im,
    const float* __restrict__ iv,
    const float* __restrict__ b2l, const float* __restrict__ og,
    const float* __restrict__ ob, const float* __restrict__ om,
    const float* __restrict__ ov,
    _Float16* __restrict__ Hio)           // h16: residual in, result out
{
    __shared__ f16x8 As[2][256];          // 8 KB   (z tile 64x32, dbuf)
    __shared__ f16x8 Bs[2][1024];         // 32 KB  (B tile 256x32, dbuf)
    __shared__ _Float16 Z1[64 * 520];     // 66.56 KB

    const int tid = threadIdx.x;
    const int m0 = blockIdx.x * 64;
    const int lane = tid & 63, wv = tid >> 6;
    const int lrow = lane & 15, lgrp = lane >> 4;
    const int wm2 = wv >> 2, wn2 = wv & 3;
    const int kq = tid & 3;
    const int brow = tid >> 2;            // 0..127

    f16x8 a_reg, b_reg0, b_reg1;

    #define SLOAD_A(K0) \
        if (tid < 256) a_reg = *(const f16x8*)(Az + (size_t)(m0 + brow) * 256 + (K0) + kq * 8);
    #define SWRITE_A(CUR) \
        if (tid < 256) As[CUR][brow * 4 + (kq ^ ((brow >> 1) & 3))] = a_reg;
    #define SLOAD_B(BASE, K0, KD) { \
        b_reg0 = *(const f16x8*)((BASE) + (size_t)brow * (KD) + (K0) + kq * 8); \
        b_reg1 = *(const f16x8*)((BASE) + (size_t)(brow + 128) * (KD) + (K0) + kq * 8); }
    #define SWRITE_B(CUR) { \
        Bs[CUR][brow * 4 + (kq ^ ((brow >> 1) & 3))] = b_reg0; \
        Bs[CUR][(brow + 128) * 4 + (kq ^ (((brow + 128) >> 1) & 3))] = b_reg1; }

    const f32x4 zero4 = {0.0f, 0.0f, 0.0f, 0.0f};

    // ---------------- phase 1: Z1 = relu(bn1(z @ w1 + b1)), two 256-col halves -----
    #pragma unroll 1
    for (int h = 0; h < 2; ++h) {
        const _Float16* Bb = W1T + (size_t)h * 256 * 256;
        float scl1[4], shf1[4];
        #pragma unroll
        for (int ni = 0; ni < 4; ++ni) {
            const int c = h * 256 + wn2 * 64 + ni * 16 + lrow;
            const float s = ig[c] * rsqrtf(iv[c] + BN_EPS);
            scl1[ni] = s;
            shf1[ni] = s * (b1l[c] - im[c]) + ib[c];
        }
        f32x4 acc[2][4];
        #pragma unroll
        for (int i = 0; i < 2; ++i)
            #pragma unroll
            for (int j = 0; j < 4; ++j) acc[i][j] = zero4;

        SLOAD_A(0); SLOAD_B(Bb, 0, 256);
        int cur = 0;
        #pragma unroll 1
        for (int k0 = 0; k0 < 256; k0 += 32) {
            SWRITE_A(cur); SWRITE_B(cur);
            __syncthreads();
            if (k0 + 32 < 256) { SLOAD_A(k0 + 32); SLOAD_B(Bb, k0 + 32, 256); }
            f16x8 af[2], bf[4];
            #pragma unroll
            for (int mi = 0; mi < 2; ++mi) {
                const int ar = wm2 * 32 + mi * 16 + lrow;
                af[mi] = As[cur][ar * 4 + (lgrp ^ ((ar >> 1) & 3))];
            }
            #pragma unroll
            for (int ni = 0; ni < 4; ++ni) {
                const int br = wn2 * 64 + ni * 16 + lrow;
                bf[ni] = Bs[cur][br * 4 + (lgrp ^ ((br >> 1) & 3))];
            }
            #pragma unroll
            for (int mi = 0; mi < 2; ++mi)
                #pragma unroll
                for (int ni = 0; ni < 4; ++ni)
                    acc[mi][ni] = __builtin_amdgcn_mfma_f32_16x16x32_f16(af[mi], bf[ni], acc[mi][ni], 0, 0, 0);
            cur ^= 1;
        }
        // epilogue -> Z1 (fp16, relu)
        #pragma unroll
        for (int mi = 0; mi < 2; ++mi)
            #pragma unroll
            for (int j = 0; j < 4; ++j) {
                const int row = wm2 * 32 + mi * 16 + lgrp * 4 + j;
                #pragma unroll
                for (int ni = 0; ni < 4; ++ni) {
                    const int col = h * 256 + wn2 * 64 + ni * 16 + lrow;
                    Z1[row * 520 + col] =
                        (_Float16)fmaxf(scl1[ni] * acc[mi][ni][j] + shf1[ni], 0.0f);
                }
            }
        __syncthreads();   // Z1 half visible; Bs reads done before reuse
    }

    // ---------------- phase 2: out = relu(bn2(Z1 @ w2 + b2)) + res ----------------
    float scl2[4], shf2[4];
    #pragma unroll
    for (int ni = 0; ni < 4; ++ni) {
        const int c = wn2 * 64 + ni * 16 + lrow;
        const float s = og[c] * rsqrtf(ov[c] + BN_EPS);
        scl2[ni] = s;
        shf2[ni] = s * (b2l[c] - om[c]) + ob[c];
    }
    f32x4 acc2[2][4];
    #pragma unroll
    for (int i = 0; i < 2; ++i)
        #pragma unroll
        for (int j = 0; j < 4; ++j) acc2[i][j] = zero4;

    SLOAD_B(W2T, 0, 512);
    int cur = 0;
    #pragma unroll 1
    for (int k0 = 0; k0 < 512; k0 += 32) {
        SWRITE_B(cur);
        __syncthreads();
        if (k0 + 32 < 512) { SLOAD_B(W2T, k0 + 32, 512); }
        f16x8 af[2], bf[4];
        #pragma unroll
        for (int mi = 0; mi < 2; ++mi) {
            const int ar = wm2 * 32 + mi * 16 + lrow;
            af[mi] = *(const f16x8*)&Z1[(size_t)ar * 520 + k0 + lgrp * 8];
        }
        #pragma unroll
        for (int ni = 0; ni < 4; ++ni) {
            const int br = wn2 * 64 + ni * 16 + lrow;
            bf[ni] = Bs[cur][br * 4 + (lgrp ^ ((br >> 1) & 3))];
        }
        #pragma unroll
        for (int mi = 0; mi < 2; ++mi)
            #pragma unroll
            for (int ni = 0; ni < 4; ++ni)
                acc2[mi][ni] = __builtin_amdgcn_mfma_f32_16x16x32_f16(af[mi], bf[ni], acc2[mi][ni], 0, 0, 0);
        cur ^= 1;
    }
    #pragma unroll
    for (int mi = 0; mi < 2; ++mi)
        #pragma unroll
        for (int j = 0; j < 4; ++j) {
            const int row = m0 + wm2 * 32 + mi * 16 + lgrp * 4 + j;
            #pragma unroll
            for (int ni = 0; ni < 4; ++ni) {
                const int col = wn2 * 64 + ni * 16 + lrow;
                float v = fmaxf(scl2[ni] * acc2[mi][ni][j] + shf2[ni], 0.0f);
                v += (float)Hio[(size_t)row * H + col];
                Hio[(size_t)row * H + col] = (_Float16)v;
            }
        }
    #undef SLOAD_A
    #undef SWRITE_A
    #undef SLOAD_B
    #undef SWRITE_B
}

// ---------------- fp16 MFMA GEMM (encoder / ebond / classifier) ----------------
// EPI 0: relu(bn(acc+bias))  EPI 2: acc+bias only
template <int KDIM, int EPI>
__global__ __launch_bounds__(256, 4) void gemm_f16(
    const _Float16* __restrict__ A,
    const _Float16* __restrict__ BT,
    int Ncols,
    const float* __restrict__ bias, const float* __restrict__ bng,
    const float* __restrict__ bnb, const float* __restrict__ bnm,
    const float* __restrict__ bnv,
    _Float16* __restrict__ C16, const _Float16* __restrict__ res)
{
    __shared__ f16x8 As[2][512];
    __shared__ f16x8 Bs[2][512];

    const int tid = threadIdx.x;
    const int nt = Ncols >> 7;
    const int nwg = gridDim.x, orig = blockIdx.x;
    const int q = nwg >> 3, r = nwg & 7;
    const int xcd = orig & 7, rk = orig >> 3;
    const int wg = (xcd < r ? xcd * (q + 1) : r * (q + 1) + (xcd - r) * q) + rk;
    const int m0 = (wg / nt) * 128;
    const int n0 = (wg % nt) * 128;

    const int wid = tid >> 6, lane = tid & 63;
    const int wm = wid >> 1, wn = wid & 1;
    const int lrow = lane & 15, lgrp = lane >> 4;
    const int r0s = tid >> 2;
    const int kq  = tid & 3;
    const int sw0 = kq ^ ((r0s >> 1) & 3);
    const int sw1 = kq ^ (((r0s + 64) >> 1) & 3);

    f32x4 acc[4][4];
    const f32x4 zero4 = {0.0f, 0.0f, 0.0f, 0.0f};
    #pragma unroll
    for (int i = 0; i < 4; ++i)
        #pragma unroll
        for (int j = 0; j < 4; ++j) acc[i][j] = zero4;

    f16x8 a0, a1, b0, b1;
    #define SLOAD(K0)                                                             \
        a0 = *(const f16x8*)(A  + (size_t)(m0 + r0s) * KDIM + (K0) + kq * 8);     \
        a1 = *(const f16x8*)(A  + (size_t)(m0 + r0s + 64) * KDIM + (K0) + kq * 8);\
        b0 = *(const f16x8*)(BT + (size_t)(n0 + r0s) * KDIM + (K0) + kq * 8);     \
        b1 = *(const f16x8*)(BT + (size_t)(n0 + r0s + 64) * KDIM + (K0) + kq * 8);
    #define SWRITE(CUR)                                                           \
        As[CUR][r0s * 4 + sw0] = a0;  As[CUR][(r0s + 64) * 4 + sw1] = a1;         \
        Bs[CUR][r0s * 4 + sw0] = b0;  Bs[CUR][(r0s + 64) * 4 + sw1] = b1;

    SLOAD(0);
    int cur = 0;
    for (int k0 = 0; k0 < KDIM; k0 += 32) {
        SWRITE(cur);
        __syncthreads();
        if (k0 + 32 < KDIM) { SLOAD(k0 + 32); }
        f16x8 af[4], bf[4];
        #pragma unroll
        for (int mi = 0; mi < 4; ++mi) {
            const int ar = wm * 64 + mi * 16 + lrow;
            af[mi] = As[cur][ar * 4 + (lgrp ^ ((ar >> 1) & 3))];
        }
        #pragma unroll
        for (int ni = 0; ni < 4; ++ni) {
            const int br = wn * 64 + ni * 16 + lrow;
            bf[ni] = Bs[cur][br * 4 + (lgrp ^ ((br >> 1) & 3))];
        }
        #pragma unroll
        for (int mi = 0; mi < 4; ++mi)
            #pragma unroll
            for (int ni = 0; ni < 4; ++ni)
                acc[mi][ni] = __builtin_amdgcn_mfma_f32_16x16x32_f16(af[mi], bf[ni], acc[mi][ni], 0, 0, 0);
        cur ^= 1;
    }
    #undef SLOAD
    #undef SWRITE

    float scl[4], shf[4];
    #pragma unroll
    for (int ni = 0; ni < 4; ++ni) {
        const int c = n0 + wn * 64 + ni * 16 + lrow;
        if (EPI == 2) {
            scl[ni] = 1.0f;
            shf[ni] = bias[c];
        } else {
            const float s = bng[c] * rsqrtf(bnv[c] + BN_EPS);
            scl[ni] = s;
            shf[ni] = s * (bias[c] - bnm[c]) + bnb[c];
        }
    }
    #pragma unroll
    for (int mi = 0; mi < 4; ++mi)
        #pragma unroll
        for (int j = 0; j < 4; ++j) {
            const int row = m0 + wm * 64 + mi * 16 + lgrp * 4 + j;
            #pragma unroll
            for (int ni = 0; ni < 4; ++ni) {
                const int col = n0 + wn * 64 + ni * 16 + lrow;
                float v = scl[ni] * acc[mi][ni][j] + shf[ni];
                if (EPI != 2) v = fmaxf(v, 0.0f);
                C16[(size_t)row * Ncols + col] = (_Float16)v;
            }
        }
}

// ---------------- pooling: mean + max per graph, fp16 out ----------------
__global__ __launch_bounds__(H) void pool_kernel(const _Float16* __restrict__ h16,
                                                 const int* __restrict__ batch,
                                                 _Float16* __restrict__ p16) {
    const int g = blockIdx.x;
    const int c = threadIdx.x;
    int lo, hi;
    {
        int a = 0, b = NA;
        while (a < b) { int mid = (a + b) >> 1; if (batch[mid] < g) a = mid + 1; else b = mid; }
        lo = a;
        b = NA;
        while (a < b) { int mid = (a + b) >> 1; if (batch[mid] < g + 1) a = mid + 1; else b = mid; }
        hi = a;
    }
    float sum = 0.0f, mx = -INFINITY;
    for (int n = lo; n < hi; ++n) {
        const float v = (float)h16[(size_t)n * H + c];
        sum += v;
        mx = fmaxf(mx, v);
    }
    const int cnt = hi - lo;
    const float mean = (cnt > 0) ? sum / (float)cnt : 0.0f;
    if (cnt == 0) mx = 0.0f;
    p16[(size_t)g * H2 + c] = (_Float16)mean;
    p16[(size_t)g * H2 + H + c] = (_Float16)mx;
}

// ---------------- final linear ----------------
__global__ __launch_bounds__(64) void final_out(const _Float16* __restrict__ q2,
                                                const float* __restrict__ w,
                                                const float* __restrict__ b,
                                                float* __restrict__ out) {
    const int g = blockIdx.x;
    const int lane = threadIdx.x;
    float acc = (float)q2[(size_t)g * 128 + lane] * w[lane]
              + (float)q2[(size_t)g * 128 + 64 + lane] * w[64 + lane];
    #pragma unroll
    for (int off = 32; off > 0; off >>= 1) acc += __shfl_down(acc, off);
    if (lane == 0) out[g] = acc + b[0];
}

// ---------------- launch ----------------
extern "C" void kernel_launch(void* const* d_in, const int* in_sizes, int n_in,
                              void* d_out, int out_size, void* d_ws, size_t ws_size,
                              hipStream_t stream) {
    const float* x      = (const float*)d_in[0];
    const int*   ei     = (const int*)d_in[1];
    const int*   batch  = (const int*)d_in[2];
    const float* eattr  = (const float*)d_in[3];
    const float* enc_w  = (const float*)d_in[4];
    const float* enc_b  = (const float*)d_in[5];
    const float* bond_w = (const float*)d_in[6];
    const float* bond_b = (const float*)d_in[7];
    const float* eps    = (const float*)d_in[8];
    const float* w1     = (const float*)d_in[9];
    const float* b1     = (const float*)d_in[10];
    const float* ibn_g  = (const float*)d_in[11];
    const float* ibn_b  = (const float*)d_in[12];
    const float* ibn_m  = (const float*)d_in[13];
    const float* ibn_v  = (const float*)d_in[14];
    const float* w2     = (const float*)d_in[15];
    const float* b2     = (const float*)d_in[16];
    const float* obn_g  = (const float*)d_in[17];
    const float* obn_b  = (const float*)d_in[18];
    const float* obn_m  = (const float*)d_in[19];
    const float* obn_v  = (const float*)d_in[20];
    const float* cw1    = (const float*)d_in[21];
    const float* cb1    = (const float*)d_in[22];
    const float* c1g    = (const float*)d_in[23];
    const float* c1b    = (const float*)d_in[24];
    const float* c1m    = (const float*)d_in[25];
    const float* c1v    = (const float*)d_in[26];
    const float* cw2    = (const float*)d_in[27];
    const float* cb2    = (const float*)d_in[28];
    const float* c2g    = (const float*)d_in[29];
    const float* c2b    = (const float*)d_in[30];
    const float* c2m    = (const float*)d_in[31];
    const float* c2v    = (const float*)d_in[32];
    const float* cw3    = (const float*)d_in[33];
    const float* cb3    = (const float*)d_in[34];
    float* out = (float*)d_out;

    // ---- workspace layout (fp16 datapath; no global z1 anymore) ----
    const size_t WTE       = (size_t)NL * H * H2;
    const size_t CW1E      = (size_t)H2 * H;
    const size_t CW2E      = (size_t)H * (H / 2);
    const size_t EWE       = (size_t)H * KP;
    const size_t BWE       = (size_t)H * KP;
    const size_t wt_bytes  = (2 * WTE + CW1E + CW2E + EWE + BWE) * 2;
    const size_t csr_words = (size_t)3 * NA + 1 + 2 * (size_t)NE + 63;
    const size_t csr_bytes = csr_words * 4;
    const size_t eb_bytes  = (size_t)NE * H * 2;             // 134 MB
    const size_t h16_bytes = (size_t)NA * H * 2;             // 67 MB
    const size_t z_bytes   = (size_t)NA * H * 2;             // 67 MB
    const size_t x16_bytes = (size_t)NA * KP * 2;            // 8.4 MB
    const size_t ea_bytes  = (size_t)NE * KP * 2;            // 16.8 MB
    const size_t need_full = wt_bytes + csr_bytes + eb_bytes + h16_bytes + z_bytes
                           + x16_bytes + ea_bytes;

    char* buf;
    if (ws_size >= need_full) { buf = (char*)d_ws; }
    else if (g_buf)           { buf = g_buf; }
    else                      { buf = (char*)d_ws; }

    _Float16* w1T  = (_Float16*)buf;
    _Float16* w2T  = w1T + WTE;
    _Float16* cw1T = w2T + WTE;
    _Float16* cw2T = cw1T + CW1E;
    _Float16* encT = cw2T + CW2E;
    _Float16* bndT = encT + EWE;
    int*  deg    = (int*)(buf + wt_bytes);
    int*  rowptr = deg + NA;
    int*  cursor = rowptr + NA + 1;
    int2* se     = (int2*)(cursor + NA);
    _Float16* eb  = (_Float16*)(buf + wt_bytes + csr_bytes);
    _Float16* h16 = (_Float16*)((char*)eb + eb_bytes);
    _Float16* z   = (_Float16*)((char*)h16 + h16_bytes);
    _Float16* x16  = (_Float16*)((char*)z + z_bytes);
    _Float16* ea16 = (_Float16*)((char*)x16 + x16_bytes);

    // classifier buffers alias z (dead after last fused layer consumed it)
    _Float16* p16 = z;                        // NG*H2
    _Float16* q1  = p16 + (size_t)NG * H2;    // NG*H
    _Float16* q2  = q1 + (size_t)NG * H;      // NG*(H/2)

    // ---- weight prep (transpose to fp16), once per call ----
    prep_w_all<<<dim3(H / 32, H2 / 32, NL), 256, 0, stream>>>(w1, H, H2, w1T);
    prep_w_all<<<dim3(H2 / 32, H / 32, NL), 256, 0, stream>>>(w2, H2, H, w2T);
    prep_w_all<<<dim3(H2 / 32, H / 32, 1), 256, 0, stream>>>(cw1, H2, H, cw1T);
    prep_w_all<<<dim3(H / 32, H / 64, 1), 256, 0, stream>>>(cw2, H, H / 2, cw2T);
    prep_wpad<<<1, 256, 0, stream>>>(enc_w, FN, encT);
    prep_wpad<<<1, 256, 0, stream>>>(bond_w, FE, bndT);

    // ---- CSR build ----
    hipMemsetAsync(deg, 0, (size_t)NA * 4, stream);
    count_deg<<<NE / 256, 256, 0, stream>>>(ei, deg);
    scan_deg<<<1, 1024, 0, stream>>>(deg, rowptr, cursor);
    fill_elist<<<NE / 256, 256, 0, stream>>>(ei, cursor, se);

    // ---- inputs to fp16 (padded K=32) ----
    prep_x16<<<NA / 64, 256, 0, stream>>>(x, x16);
    prep_ea16<<<NE / 64, 256, 0, stream>>>(eattr, se, ea16);

    // ---- encoder + bond encoding as MFMA GEMMs ----
    gemm_f16<KP, 2><<<(NA / 128) * (H / 128), 256, 0, stream>>>(
        x16, encT, H, enc_b, nullptr, nullptr, nullptr, nullptr, h16, nullptr);
    gemm_f16<KP, 2><<<(NE / 128) * (H / 128), 256, 0, stream>>>(
        ea16, bndT, H, bond_b, nullptr, nullptr, nullptr, nullptr, eb, nullptr);

    for (int l = 0; l < NL; ++l) {
        gine_msg<<<NA / 4, 256, 0, stream>>>(h16, eb, se, rowptr, eps, l, z);
        fused_mlp<<<NA / 64, 512, 0, stream>>>(
            z, w1T + (size_t)l * H * H2, w2T + (size_t)l * H2 * H,
            b1 + (size_t)l * H2, ibn_g + (size_t)l * H2, ibn_b + (size_t)l * H2,
            ibn_m + (size_t)l * H2, ibn_v + (size_t)l * H2,
            b2 + (size_t)l * H, obn_g + (size_t)l * H, obn_b + (size_t)l * H,
            obn_m + (size_t)l * H, obn_v + (size_t)l * H,
            h16);
    }

    pool_kernel<<<NG, H, 0, stream>>>(h16, batch, p16);
    gemm_f16<H2, 0><<<(NG / 128) * (H / 128), 256, 0, stream>>>(
        p16, cw1T, H, cb1, c1g, c1b, c1m, c1v, q1, nullptr);
    gemm_f16<H, 0><<<(NG / 128) * ((H / 2) / 128), 256, 0, stream>>>(
        q1, cw2T, H / 2, cb2, c2g, c2b, c2m, c2v, q2, nullptr);
    final_out<<<NG, 64, 0, stream>>>(q2, cw3, cb3, out);
}

// Round 13
// 1287.529 us; speedup vs baseline: 1.6073x; 1.0004x over previous
//
#include <hip/hip_runtime.h>
#include <math.h>

#define NA 131072   // atoms
#define NE 262144   // edges
#define NG 4096     // graphs
#define FN 30
#define FE 11
#define H  256
#define H2 512
#define NL 5
#define BN_EPS 1e-5f
#define KP 32       // padded K for encoder/bond GEMMs

typedef _Float16 f16x8 __attribute__((ext_vector_type(8)));
typedef _Float16 f16x4 __attribute__((ext_vector_type(4)));
typedef float f32x4 __attribute__((ext_vector_type(4)));

// ---- private fallback workspace, allocated ONCE at library load ----
static char* g_buf = nullptr;
__attribute__((constructor)) static void _alloc_private_ws() {
    void* p = nullptr;
    if (hipMalloc(&p, (size_t)320 * 1024 * 1024) == hipSuccess) g_buf = (char*)p;
}

// ---------------- weight prep: transpose to fp16 [N][K], layer via grid.z ----------
__global__ __launch_bounds__(256) void prep_w_all(const float* __restrict__ w, int K, int N,
                                                  _Float16* __restrict__ hT) {
    const float* wl = w + (size_t)blockIdx.z * K * N;
    _Float16* hTl = hT + (size_t)blockIdx.z * K * N;
    __shared__ float t[32][33];
    const int k0 = blockIdx.x * 32, n0 = blockIdx.y * 32;
    const int tx = threadIdx.x & 31, ty = threadIdx.x >> 5;   // ty 0..7
    #pragma unroll
    for (int i = 0; i < 4; ++i)
        t[ty + i * 8][tx] = wl[(size_t)(k0 + ty + i * 8) * N + n0 + tx];
    __syncthreads();
    #pragma unroll
    for (int i = 0; i < 4; ++i)
        hTl[(size_t)(n0 + ty + i * 8) * K + k0 + tx] = (_Float16)t[tx][ty + i * 8];
}

// ---- small-K weight pad+transpose: w [K_IN][H] fp32 -> wT [H][KP] fp16 (zero pad) ----
__global__ __launch_bounds__(256) void prep_wpad(const float* __restrict__ w, int K_IN,
                                                 _Float16* __restrict__ wT) {
    const int n = threadIdx.x;
    #pragma unroll
    for (int kk = 0; kk < KP / 8; ++kk) {
        f16x8 v;
        #pragma unroll
        for (int j = 0; j < 8; ++j) {
            const int k = kk * 8 + j;
            v[j] = (k < K_IN) ? (_Float16)w[(size_t)k * H + n] : (_Float16)0.0f;
        }
        *(f16x8*)(wT + (size_t)n * KP + kk * 8) = v;
    }
}

// ---- x [NA][FN] fp32 -> x16 [NA][KP] fp16 padded ----
__global__ __launch_bounds__(256) void prep_x16(const float* __restrict__ x,
                                                _Float16* __restrict__ x16) {
    const int row = blockIdx.x * 64 + (threadIdx.x >> 2);
    const int g = threadIdx.x & 3;
    f16x8 v;
    #pragma unroll
    for (int j = 0; j < 8; ++j) {
        const int c = g * 8 + j;
        v[j] = (c < FN) ? (_Float16)x[(size_t)row * FN + c] : (_Float16)0.0f;
    }
    *(f16x8*)(x16 + (size_t)row * KP + g * 8) = v;
}

// ---- eattr permuted to CSR slot order + padded ----
__global__ __launch_bounds__(256) void prep_ea16(const float* __restrict__ eattr,
                                                 const int2* __restrict__ se,
                                                 _Float16* __restrict__ ea16) {
    const int t = blockIdx.x * 64 + (threadIdx.x >> 2);
    const int g = threadIdx.x & 3;
    const int e = se[t].y;
    f16x8 v;
    #pragma unroll
    for (int j = 0; j < 8; ++j) {
        const int c = g * 8 + j;
        v[j] = (c < FE) ? (_Float16)eattr[(size_t)e * FE + c] : (_Float16)0.0f;
    }
    *(f16x8*)(ea16 + (size_t)t * KP + g * 8) = v;
}

// ---------------- CSR build (once per call) ----------------
__global__ __launch_bounds__(256) void count_deg(const int* __restrict__ ei,
                                                 int* __restrict__ deg) {
    const int e = blockIdx.x * 256 + threadIdx.x;
    if (e < NE) atomicAdd(&deg[ei[NE + e]], 1);
}

__global__ __launch_bounds__(1024) void scan_deg(const int* __restrict__ deg,
                                                 int* __restrict__ rowptr,
                                                 int* __restrict__ cursor) {
    __shared__ int part[1024];
    const int t = threadIdx.x;
    const int base = t * 128;               // 1024*128 == NA
    int s = 0;
    #pragma unroll 8
    for (int i = 0; i < 128; ++i) s += deg[base + i];
    part[t] = s;
    __syncthreads();
    for (int off = 1; off < 1024; off <<= 1) {
        const int v = (t >= off) ? part[t - off] : 0;
        __syncthreads();
        part[t] += v;
        __syncthreads();
    }
    int run = (t == 0) ? 0 : part[t - 1];
    #pragma unroll 8
    for (int i = 0; i < 128; ++i) {
        rowptr[base + i] = run;
        cursor[base + i] = run;
        run += deg[base + i];
    }
    if (t == 1023) rowptr[NA] = run;        // == NE
}

__global__ __launch_bounds__(256) void fill_elist(const int* __restrict__ ei,
                                                  int* __restrict__ cursor,
                                                  int2* __restrict__ se) {
    const int e = blockIdx.x * 256 + threadIdx.x;
    if (e < NE) {
        const int src = ei[e];
        const int pos = atomicAdd(&cursor[ei[NE + e]], 1);
        se[pos] = make_int2(src, e);
    }
}

// ---- GINE aggregation: wave-per-dst; sequential ebond stream + h16 gather ----
__global__ __launch_bounds__(256) void gine_msg(const _Float16* __restrict__ h16,
                                                const _Float16* __restrict__ eb,
                                                const int2* __restrict__ se,
                                                const int* __restrict__ rowptr,
                                                const float* __restrict__ eps, int l,
                                                _Float16* __restrict__ z) {
    const int dst = blockIdx.x * 4 + (threadIdx.x >> 6);
    const int lane = threadIdx.x & 63;
    const int c = lane * 4;
    const float sc = 1.0f + eps[l];
    const f16x4 hv = *(const f16x4*)(h16 + (size_t)dst * H + c);
    float4 acc;
    acc.x = sc * (float)hv.x; acc.y = sc * (float)hv.y;
    acc.z = sc * (float)hv.z; acc.w = sc * (float)hv.w;
    const int lo = rowptr[dst], hi = rowptr[dst + 1];
    for (int t = lo; t < hi; ++t) {
        const int src = se[t].x;                               // wave-uniform
        const f16x4 hs = *(const f16x4*)(h16 + (size_t)src * H + c);
        const f16x4 ev = *(const f16x4*)(eb + (size_t)t * H + c);
        acc.x += fmaxf((float)hs.x + (float)ev.x, 0.0f);
        acc.y += fmaxf((float)hs.y + (float)ev.y, 0.0f);
        acc.z += fmaxf((float)hs.z + (float)ev.z, 0.0f);
        acc.w += fmaxf((float)hs.w + (float)ev.w, 0.0f);
    }
    f16x4 o;
    o.x = (_Float16)acc.x; o.y = (_Float16)acc.y;
    o.z = (_Float16)acc.z; o.w = (_Float16)acc.w;
    *(f16x4*)(z + (size_t)dst * H + c) = o;
}

// ================= fused per-layer MLP v2 ======================================
// h16 = relu(bn2(relu(bn1(z@w1))@w2)) + h16.  64-row M-tile, 512 thr = 8 waves (2x4).
// Phase-1 A (z tile) fully PRELOADED to registers (16 f16x8/lane, 16 loads in flight).
// B panels staged depth-2 (two reg sets, 2-step-unrolled loop). Z1 kept in LDS.
// LDS: Bs 32 KB + Z1 66.6 KB = 98.6 KB -> 1 block/CU; launch_bounds(512,1) frees VGPRs.
__global__ __launch_bounds__(512, 1) void fused_mlp(
    const _Float16* __restrict__ Az,      // z [NA][256]
    const _Float16* __restrict__ W1T,     // [512][256]
    const _Float16* __restrict__ W2T,     // [256][512]
    const float* __restrict__ b1l, const float* __restrict__ ig,
    const float* __restrict__ ib, const float* __restrict__ im,
    const float* __restrict__ iv,
    const float* __restrict__ b2l, const float* __restrict__ og,
    const float* __restrict__ ob, const float* __restrict__ om,
    const float* __restrict__ ov,
    _Float16* __restrict__ Hio)           // h16: residual in, result out
{
    __shared__ f16x8 Bs[2][1024];         // 32 KB  (B tile 256x32, dbuf)
    __shared__ _Float16 Z1[64 * 520];     // 66.56 KB

    const int tid = threadIdx.x;
    const int m0 = blockIdx.x * 64;
    const int lane = tid & 63, wv = tid >> 6;
    const int lrow = lane & 15, lgrp = lane >> 4;
    const int wm2 = wv >> 2, wn2 = wv & 3;
    const int kq = tid & 3;
    const int brow = tid >> 2;            // 0..127
    const int bsw0 = brow * 4 + (kq ^ ((brow >> 1) & 3));
    const int bsw1 = (brow + 128) * 4 + (kq ^ (((brow + 128) >> 1) & 3));

    // ---- preload ALL phase-1 A fragments (z tile 64x256): 16 loads in flight ----
    f16x8 afA0[8], afA1[8];
    {
        const int ar0 = m0 + wm2 * 32 + lrow;        // mi = 0
        const int ar1 = ar0 + 16;                     // mi = 1
        #pragma unroll
        for (int ks = 0; ks < 8; ++ks) {
            afA0[ks] = *(const f16x8*)(Az + (size_t)ar0 * 256 + ks * 32 + lgrp * 8);
            afA1[ks] = *(const f16x8*)(Az + (size_t)ar1 * 256 + ks * 32 + lgrp * 8);
        }
    }

    f16x8 bA0, bB0, bA1, bB1;
    #define SLOAD_B0(BASE, K0, KD) { \
        bA0 = *(const f16x8*)((BASE) + (size_t)brow * (KD) + (K0) + kq * 8); \
        bB0 = *(const f16x8*)((BASE) + (size_t)(brow + 128) * (KD) + (K0) + kq * 8); }
    #define SLOAD_B1(BASE, K0, KD) { \
        bA1 = *(const f16x8*)((BASE) + (size_t)brow * (KD) + (K0) + kq * 8); \
        bB1 = *(const f16x8*)((BASE) + (size_t)(brow + 128) * (KD) + (K0) + kq * 8); }
    #define SWRITE_B0(CUR) { Bs[CUR][bsw0] = bA0; Bs[CUR][bsw1] = bB0; }
    #define SWRITE_B1(CUR) { Bs[CUR][bsw0] = bA1; Bs[CUR][bsw1] = bB1; }

    const f32x4 zero4 = {0.0f, 0.0f, 0.0f, 0.0f};

    // ---------------- phase 1: Z1 = relu(bn1(z @ w1 + b1)), two 256-col halves -----
    #pragma unroll 1
    for (int h = 0; h < 2; ++h) {
        const _Float16* Bb = W1T + (size_t)h * 256 * 256;
        float scl1[4], shf1[4];
        #pragma unroll
        for (int ni = 0; ni < 4; ++ni) {
            const int c = h * 256 + wn2 * 64 + ni * 16 + lrow;
            const float s = ig[c] * rsqrtf(iv[c] + BN_EPS);
            scl1[ni] = s;
            shf1[ni] = s * (b1l[c] - im[c]) + ib[c];
        }
        f32x4 acc[2][4];
        #pragma unroll
        for (int i = 0; i < 2; ++i)
            #pragma unroll
            for (int j = 0; j < 4; ++j) acc[i][j] = zero4;

        SLOAD_B0(Bb, 0, 256);
        SLOAD_B1(Bb, 32, 256);
        #pragma unroll
        for (int kp = 0; kp < 4; ++kp) {           // fully unrolled: static bufs/ks
            // even step: ks = 2*kp, buf = kp&1? ... cur toggles: step index 2kp -> buf (2kp)&1
            {
                const int cur = 0;                 // steps 0,2,4,6 -> buf 0
                SWRITE_B0(cur);
                __syncthreads();
                if (kp < 3) SLOAD_B0(Bb, (2 * kp + 2) * 32, 256);
                f16x8 bf[4];
                #pragma unroll
                for (int ni = 0; ni < 4; ++ni) {
                    const int br = wn2 * 64 + ni * 16 + lrow;
                    bf[ni] = Bs[cur][br * 4 + (lgrp ^ ((br >> 1) & 3))];
                }
                #pragma unroll
                for (int ni = 0; ni < 4; ++ni) {
                    acc[0][ni] = __builtin_amdgcn_mfma_f32_16x16x32_f16(afA0[2 * kp], bf[ni], acc[0][ni], 0, 0, 0);
                    acc[1][ni] = __builtin_amdgcn_mfma_f32_16x16x32_f16(afA1[2 * kp], bf[ni], acc[1][ni], 0, 0, 0);
                }
            }
            // odd step: ks = 2*kp+1 -> buf 1
            {
                const int cur = 1;
                SWRITE_B1(cur);
                __syncthreads();
                if (kp < 3) SLOAD_B1(Bb, (2 * kp + 3) * 32, 256);
                f16x8 bf[4];
                #pragma unroll
                for (int ni = 0; ni < 4; ++ni) {
                    const int br = wn2 * 64 + ni * 16 + lrow;
                    bf[ni] = Bs[cur][br * 4 + (lgrp ^ ((br >> 1) & 3))];
                }
                #pragma unroll
                for (int ni = 0; ni < 4; ++ni) {
                    acc[0][ni] = __builtin_amdgcn_mfma_f32_16x16x32_f16(afA0[2 * kp + 1], bf[ni], acc[0][ni], 0, 0, 0);
                    acc[1][ni] = __builtin_amdgcn_mfma_f32_16x16x32_f16(afA1[2 * kp + 1], bf[ni], acc[1][ni], 0, 0, 0);
                }
            }
        }
        // epilogue -> Z1 (fp16, relu)
        #pragma unroll
        for (int mi = 0; mi < 2; ++mi)
            #pragma unroll
            for (int j = 0; j < 4; ++j) {
                const int row = wm2 * 32 + mi * 16 + lgrp * 4 + j;
                #pragma unroll
                for (int ni = 0; ni < 4; ++ni) {
                    const int col = h * 256 + wn2 * 64 + ni * 16 + lrow;
                    Z1[row * 520 + col] =
                        (_Float16)fmaxf(scl1[ni] * acc[mi][ni][j] + shf1[ni], 0.0f);
                }
            }
        __syncthreads();   // Z1 half visible; Bs reads drained before reuse
    }

    // ---------------- phase 2: out = relu(bn2(Z1 @ w2 + b2)) + res ----------------
    float scl2[4], shf2[4];
    #pragma unroll
    for (int ni = 0; ni < 4; ++ni) {
        const int c = wn2 * 64 + ni * 16 + lrow;
        const float s = og[c] * rsqrtf(ov[c] + BN_EPS);
        scl2[ni] = s;
        shf2[ni] = s * (b2l[c] - om[c]) + ob[c];
    }
    f32x4 acc2[2][4];
    #pragma unroll
    for (int i = 0; i < 2; ++i)
        #pragma unroll
        for (int j = 0; j < 4; ++j) acc2[i][j] = zero4;

    SLOAD_B0(W2T, 0, 512);
    SLOAD_B1(W2T, 32, 512);
    #pragma unroll
    for (int kp = 0; kp < 8; ++kp) {               // K=512: 8 pairs, fully unrolled
        {
            const int cur = 0;
            SWRITE_B0(cur);
            __syncthreads();
            if (kp < 7) SLOAD_B0(W2T, (2 * kp + 2) * 32, 512);
            const int k0 = 2 * kp * 32;
            f16x8 af[2], bf[4];
            #pragma unroll
            for (int mi = 0; mi < 2; ++mi) {
                const int ar = wm2 * 32 + mi * 16 + lrow;
                af[mi] = *(const f16x8*)&Z1[(size_t)ar * 520 + k0 + lgrp * 8];
            }
            #pragma unroll
            for (int ni = 0; ni < 4; ++ni) {
                const int br = wn2 * 64 + ni * 16 + lrow;
                bf[ni] = Bs[cur][br * 4 + (lgrp ^ ((br >> 1) & 3))];
            }
            #pragma unroll
            for (int mi = 0; mi < 2; ++mi)
                #pragma unroll
                for (int ni = 0; ni < 4; ++ni)
                    acc2[mi][ni] = __builtin_amdgcn_mfma_f32_16x16x32_f16(af[mi], bf[ni], acc2[mi][ni], 0, 0, 0);
        }
        {
            const int cur = 1;
            SWRITE_B1(cur);
            __syncthreads();
            if (kp < 7) SLOAD_B1(W2T, (2 * kp + 3) * 32, 512);
            const int k0 = (2 * kp + 1) * 32;
            f16x8 af[2], bf[4];
            #pragma unroll
            for (int mi = 0; mi < 2; ++mi) {
                const int ar = wm2 * 32 + mi * 16 + lrow;
                af[mi] = *(const f16x8*)&Z1[(size_t)ar * 520 + k0 + lgrp * 8];
            }
            #pragma unroll
            for (int ni = 0; ni < 4; ++ni) {
                const int br = wn2 * 64 + ni * 16 + lrow;
                bf[ni] = Bs[cur][br * 4 + (lgrp ^ ((br >> 1) & 3))];
            }
            #pragma unroll
            for (int mi = 0; mi < 2; ++mi)
                #pragma unroll
                for (int ni = 0; ni < 4; ++ni)
                    acc2[mi][ni] = __builtin_amdgcn_mfma_f32_16x16x32_f16(af[mi], bf[ni], acc2[mi][ni], 0, 0, 0);
        }
    }
    #pragma unroll
    for (int mi = 0; mi < 2; ++mi)
        #pragma unroll
        for (int j = 0; j < 4; ++j) {
            const int row = m0 + wm2 * 32 + mi * 16 + lgrp * 4 + j;
            #pragma unroll
            for (int ni = 0; ni < 4; ++ni) {
                const int col = wn2 * 64 + ni * 16 + lrow;
                float v = fmaxf(scl2[ni] * acc2[mi][ni][j] + shf2[ni], 0.0f);
                v += (float)Hio[(size_t)row * H + col];
                Hio[(size_t)row * H + col] = (_Float16)v;
            }
        }
    #undef SLOAD_B0
    #undef SLOAD_B1
    #undef SWRITE_B0
    #undef SWRITE_B1
}

// ---------------- fp16 MFMA GEMM (encoder / ebond / classifier) ----------------
// EPI 0: relu(bn(acc+bias))  EPI 2: acc+bias only
template <int KDIM, int EPI>
__global__ __launch_bounds__(256, 4) void gemm_f16(
    const _Float16* __restrict__ A,
    const _Float16* __restrict__ BT,
    int Ncols,
    const float* __restrict__ bias, const float* __restrict__ bng,
    const float* __restrict__ bnb, const float* __restrict__ bnm,
    const float* __restrict__ bnv,
    _Float16* __restrict__ C16, const _Float16* __restrict__ res)
{
    __shared__ f16x8 As[2][512];
    __shared__ f16x8 Bs[2][512];

    const int tid = threadIdx.x;
    const int nt = Ncols >> 7;
    const int nwg = gridDim.x, orig = blockIdx.x;
    const int q = nwg >> 3, r = nwg & 7;
    const int xcd = orig & 7, rk = orig >> 3;
    const int wg = (xcd < r ? xcd * (q + 1) : r * (q + 1) + (xcd - r) * q) + rk;
    const int m0 = (wg / nt) * 128;
    const int n0 = (wg % nt) * 128;

    const int wid = tid >> 6, lane = tid & 63;
    const int wm = wid >> 1, wn = wid & 1;
    const int lrow = lane & 15, lgrp = lane >> 4;
    const int r0s = tid >> 2;
    const int kq  = tid & 3;
    const int sw0 = kq ^ ((r0s >> 1) & 3);
    const int sw1 = kq ^ (((r0s + 64) >> 1) & 3);

    f32x4 acc[4][4];
    const f32x4 zero4 = {0.0f, 0.0f, 0.0f, 0.0f};
    #pragma unroll
    for (int i = 0; i < 4; ++i)
        #pragma unroll
        for (int j = 0; j < 4; ++j) acc[i][j] = zero4;

    f16x8 a0, a1, b0, b1;
    #define SLOAD(K0)                                                             \
        a0 = *(const f16x8*)(A  + (size_t)(m0 + r0s) * KDIM + (K0) + kq * 8);     \
        a1 = *(const f16x8*)(A  + (size_t)(m0 + r0s + 64) * KDIM + (K0) + kq * 8);\
        b0 = *(const f16x8*)(BT + (size_t)(n0 + r0s) * KDIM + (K0) + kq * 8);     \
        b1 = *(const f16x8*)(BT + (size_t)(n0 + r0s + 64) * KDIM + (K0) + kq * 8);
    #define SWRITE(CUR)                                                           \
        As[CUR][r0s * 4 + sw0] = a0;  As[CUR][(r0s + 64) * 4 + sw1] = a1;         \
        Bs[CUR][r0s * 4 + sw0] = b0;  Bs[CUR][(r0s + 64) * 4 + sw1] = b1;

    SLOAD(0);
    int cur = 0;
    for (int k0 = 0; k0 < KDIM; k0 += 32) {
        SWRITE(cur);
        __syncthreads();
        if (k0 + 32 < KDIM) { SLOAD(k0 + 32); }
        f16x8 af[4], bf[4];
        #pragma unroll
        for (int mi = 0; mi < 4; ++mi) {
            const int ar = wm * 64 + mi * 16 + lrow;
            af[mi] = As[cur][ar * 4 + (lgrp ^ ((ar >> 1) & 3))];
        }
        #pragma unroll
        for (int ni = 0; ni < 4; ++ni) {
            const int br = wn * 64 + ni * 16 + lrow;
            bf[ni] = Bs[cur][br * 4 + (lgrp ^ ((br >> 1) & 3))];
        }
        #pragma unroll
        for (int mi = 0; mi < 4; ++mi)
            #pragma unroll
            for (int ni = 0; ni < 4; ++ni)
                acc[mi][ni] = __builtin_amdgcn_mfma_f32_16x16x32_f16(af[mi], bf[ni], acc[mi][ni], 0, 0, 0);
        cur ^= 1;
    }
    #undef SLOAD
    #undef SWRITE

    float scl[4], shf[4];
    #pragma unroll
    for (int ni = 0; ni < 4; ++ni) {
        const int c = n0 + wn * 64 + ni * 16 + lrow;
        if (EPI == 2) {
            scl[ni] = 1.0f;
            shf[ni] = bias[c];
        } else {
            const float s = bng[c] * rsqrtf(bnv[c] + BN_EPS);
            scl[ni] = s;
            shf[ni] = s * (bias[c] - bnm[c]) + bnb[c];
        }
    }
    #pragma unroll
    for (int mi = 0; mi < 4; ++mi)
        #pragma unroll
        for (int j = 0; j < 4; ++j) {
            const int row = m0 + wm * 64 + mi * 16 + lgrp * 4 + j;
            #pragma unroll
            for (int ni = 0; ni < 4; ++ni) {
                const int col = n0 + wn * 64 + ni * 16 + lrow;
                float v = scl[ni] * acc[mi][ni][j] + shf[ni];
                if (EPI != 2) v = fmaxf(v, 0.0f);
                C16[(size_t)row * Ncols + col] = (_Float16)v;
            }
        }
}

// ---------------- pooling: mean + max per graph, fp16 out ----------------
__global__ __launch_bounds__(H) void pool_kernel(const _Float16* __restrict__ h16,
                                                 const int* __restrict__ batch,
                                                 _Float16* __restrict__ p16) {
    const int g = blockIdx.x;
    const int c = threadIdx.x;
    int lo, hi;
    {
        int a = 0, b = NA;
        while (a < b) { int mid = (a + b) >> 1; if (batch[mid] < g) a = mid + 1; else b = mid; }
        lo = a;
        b = NA;
        while (a < b) { int mid = (a + b) >> 1; if (batch[mid] < g + 1) a = mid + 1; else b = mid; }
        hi = a;
    }
    float sum = 0.0f, mx = -INFINITY;
    for (int n = lo; n < hi; ++n) {
        const float v = (float)h16[(size_t)n * H + c];
        sum += v;
        mx = fmaxf(mx, v);
    }
    const int cnt = hi - lo;
    const float mean = (cnt > 0) ? sum / (float)cnt : 0.0f;
    if (cnt == 0) mx = 0.0f;
    p16[(size_t)g * H2 + c] = (_Float16)mean;
    p16[(size_t)g * H2 + H + c] = (_Float16)mx;
}

// ---------------- final linear ----------------
__global__ __launch_bounds__(64) void final_out(const _Float16* __restrict__ q2,
                                                const float* __restrict__ w,
                                                const float* __restrict__ b,
                                                float* __restrict__ out) {
    const int g = blockIdx.x;
    const int lane = threadIdx.x;
    float acc = (float)q2[(size_t)g * 128 + lane] * w[lane]
              + (float)q2[(size_t)g * 128 + 64 + lane] * w[64 + lane];
    #pragma unroll
    for (int off = 32; off > 0; off >>= 1) acc += __shfl_down(acc, off);
    if (lane == 0) out[g] = acc + b[0];
}

// ---------------- launch ----------------
extern "C" void kernel_launch(void* const* d_in, const int* in_sizes, int n_in,
                              void* d_out, int out_size, void* d_ws, size_t ws_size,
                              hipStream_t stream) {
    const float* x      = (const float*)d_in[0];
    const int*   ei     = (const int*)d_in[1];
    const int*   batch  = (const int*)d_in[2];
    const float* eattr  = (const float*)d_in[3];
    const float* enc_w  = (const float*)d_in[4];
    const float* enc_b  = (const float*)d_in[5];
    const float* bond_w = (const float*)d_in[6];
    const float* bond_b = (const float*)d_in[7];
    const float* eps    = (const float*)d_in[8];
    const float* w1     = (const float*)d_in[9];
    const float* b1     = (const float*)d_in[10];
    const float* ibn_g  = (const float*)d_in[11];
    const float* ibn_b  = (const float*)d_in[12];
    const float* ibn_m  = (const float*)d_in[13];
    const float* ibn_v  = (const float*)d_in[14];
    const float* w2     = (const float*)d_in[15];
    const float* b2     = (const float*)d_in[16];
    const float* obn_g  = (const float*)d_in[17];
    const float* obn_b  = (const float*)d_in[18];
    const float* obn_m  = (const float*)d_in[19];
    const float* obn_v  = (const float*)d_in[20];
    const float* cw1    = (const float*)d_in[21];
    const float* cb1    = (const float*)d_in[22];
    const float* c1g    = (const float*)d_in[23];
    const float* c1b    = (const float*)d_in[24];
    const float* c1m    = (const float*)d_in[25];
    const float* c1v    = (const float*)d_in[26];
    const float* cw2    = (const float*)d_in[27];
    const float* cb2    = (const float*)d_in[28];
    const float* c2g    = (const float*)d_in[29];
    const float* c2b    = (const float*)d_in[30];
    const float* c2m    = (const float*)d_in[31];
    const float* c2v    = (const float*)d_in[32];
    const float* cw3    = (const float*)d_in[33];
    const float* cb3    = (const float*)d_in[34];
    float* out = (float*)d_out;

    // ---- workspace layout (fp16 datapath; no global z1) ----
    const size_t WTE       = (size_t)NL * H * H2;
    const size_t CW1E      = (size_t)H2 * H;
    const size_t CW2E      = (size_t)H * (H / 2);
    const size_t EWE       = (size_t)H * KP;
    const size_t BWE       = (size_t)H * KP;
    const size_t wt_bytes  = (2 * WTE + CW1E + CW2E + EWE + BWE) * 2;
    const size_t csr_words = (size_t)3 * NA + 1 + 2 * (size_t)NE + 63;
    const size_t csr_bytes = csr_words * 4;
    const size_t eb_bytes  = (size_t)NE * H * 2;             // 134 MB
    const size_t h16_bytes = (size_t)NA * H * 2;             // 67 MB
    const size_t z_bytes   = (size_t)NA * H * 2;             // 67 MB
    const size_t x16_bytes = (size_t)NA * KP * 2;            // 8.4 MB
    const size_t ea_bytes  = (size_t)NE * KP * 2;            // 16.8 MB
    const size_t need_full = wt_bytes + csr_bytes + eb_bytes + h16_bytes + z_bytes
                           + x16_bytes + ea_bytes;

    char* buf;
    if (ws_size >= need_full) { buf = (char*)d_ws; }
    else if (g_buf)           { buf = g_buf; }
    else                      { buf = (char*)d_ws; }

    _Float16* w1T  = (_Float16*)buf;
    _Float16* w2T  = w1T + WTE;
    _Float16* cw1T = w2T + WTE;
    _Float16* cw2T = cw1T + CW1E;
    _Float16* encT = cw2T + CW2E;
    _Float16* bndT = encT + EWE;
    int*  deg    = (int*)(buf + wt_bytes);
    int*  rowptr = deg + NA;
    int*  cursor = rowptr + NA + 1;
    int2* se     = (int2*)(cursor + NA);
    _Float16* eb  = (_Float16*)(buf + wt_bytes + csr_bytes);
    _Float16* h16 = (_Float16*)((char*)eb + eb_bytes);
    _Float16* z   = (_Float16*)((char*)h16 + h16_bytes);
    _Float16* x16  = (_Float16*)((char*)z + z_bytes);
    _Float16* ea16 = (_Float16*)((char*)x16 + x16_bytes);

    // classifier buffers alias z (dead after last fused layer consumed it)
    _Float16* p16 = z;                        // NG*H2
    _Float16* q1  = p16 + (size_t)NG * H2;    // NG*H
    _Float16* q2  = q1 + (size_t)NG * H;      // NG*(H/2)

    // ---- weight prep (transpose to fp16), once per call ----
    prep_w_all<<<dim3(H / 32, H2 / 32, NL), 256, 0, stream>>>(w1, H, H2, w1T);
    prep_w_all<<<dim3(H2 / 32, H / 32, NL), 256, 0, stream>>>(w2, H2, H, w2T);
    prep_w_all<<<dim3(H2 / 32, H / 32, 1), 256, 0, stream>>>(cw1, H2, H, cw1T);
    prep_w_all<<<dim3(H / 32, H / 64, 1), 256, 0, stream>>>(cw2, H, H / 2, cw2T);
    prep_wpad<<<1, 256, 0, stream>>>(enc_w, FN, encT);
    prep_wpad<<<1, 256, 0, stream>>>(bond_w, FE, bndT);

    // ---- CSR build ----
    hipMemsetAsync(deg, 0, (size_t)NA * 4, stream);
    count_deg<<<NE / 256, 256, 0, stream>>>(ei, deg);
    scan_deg<<<1, 1024, 0, stream>>>(deg, rowptr, cursor);
    fill_elist<<<NE / 256, 256, 0, stream>>>(ei, cursor, se);

    // ---- inputs to fp16 (padded K=32) ----
    prep_x16<<<NA / 64, 256, 0, stream>>>(x, x16);
    prep_ea16<<<NE / 64, 256, 0, stream>>>(eattr, se, ea16);

    // ---- encoder + bond encoding as MFMA GEMMs ----
    gemm_f16<KP, 2><<<(NA / 128) * (H / 128), 256, 0, stream>>>(
        x16, encT, H, enc_b, nullptr, nullptr, nullptr, nullptr, h16, nullptr);
    gemm_f16<KP, 2><<<(NE / 128) * (H / 128), 256, 0, stream>>>(
        ea16, bndT, H, bond_b, nullptr, nullptr, nullptr, nullptr, eb, nullptr);

    for (int l = 0; l < NL; ++l) {
        gine_msg<<<NA / 4, 256, 0, stream>>>(h16, eb, se, rowptr, eps, l, z);
        fused_mlp<<<NA / 64, 512, 0, stream>>>(
            z, w1T + (size_t)l * H * H2, w2T + (size_t)l * H2 * H,
            b1 + (size_t)l * H2, ibn_g + (size_t)l * H2, ibn_b + (size_t)l * H2,
            ibn_m + (size_t)l * H2, ibn_v + (size_t)l * H2,
            b2 + (size_t)l * H, obn_g + (size_t)l * H, obn_b + (size_t)l * H,
            obn_m + (size_t)l * H, obn_v + (size_t)l * H,
            h16);
    }

    pool_kernel<<<NG, H, 0, stream>>>(h16, batch, p16);
    gemm_f16<H2, 0><<<(NG / 128) * (H / 128), 256, 0, stream>>>(
        p16, cw1T, H, cb1, c1g, c1b, c1m, c1v, q1, nullptr);
    gemm_f16<H, 0><<<(NG / 128) * ((H / 2) / 128), 256, 0, stream>>>(
        q1, cw2T, H / 2, cb2, c2g, c2b, c2m, c2v, q2, nullptr);
    final_out<<<NG, 64, 0, stream>>>(q2, cw3, cb3, out);
}